// Round 1
// baseline (1794.524 us; speedup 1.0000x reference)
//
#include <hip/hip_runtime.h>
#include <math.h>

#define N_NODES 50000
#define N_EDGES 640000
#define N_GRAPHS 2000
#define FN 64
#define FE 16
#define H 128
#define NL 2

// ---------------- static workspace ----------------
static constexpr size_t AL = 256;
static constexpr size_t alup(size_t x) { return (x + AL - 1) & ~(AL - 1); }

static constexpr size_t SZ_H      = (size_t)N_NODES * H * 4;        // 25.6 MB
static constexpr size_t SZ_PQMG   = (size_t)N_NODES * 768 * 4;      // 153.6 MB
static constexpr size_t SZ_GI     = (size_t)N_NODES * 384 * 4;      // 76.8 MB
static constexpr size_t SZ_EEXP   = (size_t)N_EDGES * 4;
static constexpr size_t SZ_NF     = (size_t)N_NODES * 4;
static constexpr size_t SZ_WBIG   = (size_t)128 * 768 * 4;
static constexpr size_t SZ_BBIG   = (size_t)768 * 4;
static constexpr size_t SZ_G128   = (size_t)N_GRAPHS * 128 * 4;
static constexpr size_t SZ_G384   = (size_t)N_GRAPHS * 384 * 4;
static constexpr size_t SZ_GF     = (size_t)N_GRAPHS * 4;
static constexpr size_t SZ_CSR    = (size_t)N_EDGES * 4;

static constexpr size_t OFF_H0    = 0;
static constexpr size_t OFF_H1    = alup(OFF_H0 + SZ_H);
static constexpr size_t OFF_PQMG  = alup(OFF_H1 + SZ_H);
static constexpr size_t OFF_GI    = alup(OFF_PQMG + SZ_PQMG);
static constexpr size_t OFF_AGGR  = alup(OFF_GI + SZ_GI);
static constexpr size_t OFF_EEXP  = alup(OFF_AGGR + SZ_H);
static constexpr size_t OFF_SSUM  = alup(OFF_EEXP + SZ_EEXP);
static constexpr size_t OFF_ES    = alup(OFF_SSUM + SZ_NF);
static constexpr size_t OFF_WBIG  = alup(OFF_ES + SZ_NF);
static constexpr size_t OFF_BBIG  = alup(OFF_WBIG + SZ_WBIG);
static constexpr size_t OFF_G0    = alup(OFF_BBIG + SZ_BBIG);
static constexpr size_t OFF_GA    = alup(OFF_G0 + SZ_G128);
static constexpr size_t OFF_CTX   = alup(OFF_GA + SZ_G128);
static constexpr size_t OFF_GICTX = alup(OFF_CTX + SZ_G128);
static constexpr size_t OFF_GHB   = alup(OFF_GICTX + SZ_G384);
static constexpr size_t OFF_GSUM  = alup(OFF_GHB + SZ_G384);
static constexpr size_t OFF_DEG   = alup(OFF_GSUM + SZ_GF);
static constexpr size_t OFF_OFFS  = alup(OFF_DEG + SZ_NF);
static constexpr size_t OFF_CUR   = alup(OFF_OFFS + SZ_NF + 4);
static constexpr size_t OFF_CSR   = alup(OFF_CUR + SZ_NF);
static constexpr size_t OFF_GHIST = alup(OFF_CSR + SZ_CSR);
static constexpr size_t OFF_GOFFS = alup(OFF_GHIST + SZ_GF);
static constexpr size_t TOTAL_WS  = alup(OFF_GOFFS + SZ_GF + 4);

__device__ unsigned char g_afp_ws[TOTAL_WS];

// ---------------- generic tiled f32 GEMM: C = act(A@B + bias) ----------------
// A [M,K] row-major, B [K,Ncol] row-major. act: 0 none, 1 relu.
#define GBM 64
#define GBN 64
#define GBK 32
__global__ __launch_bounds__(256) void gemm_f32(
    const float* __restrict__ A, const float* __restrict__ B,
    const float* __restrict__ bias, float* __restrict__ C,
    int M, int K, int Ncol, int act)
{
    __shared__ float As[GBK][GBM + 4];
    __shared__ float Bs[GBK][GBN + 4];
    const int tx = threadIdx.x & 15;
    const int ty = threadIdx.x >> 4;
    const int row0 = blockIdx.x * GBM;
    const int col0 = blockIdx.y * GBN;
    float acc[4][4] = {};
    for (int k0 = 0; k0 < K; k0 += GBK) {
        for (int i = threadIdx.x; i < GBM * GBK; i += 256) {
            int r = i / GBK, c = i % GBK;
            float v = 0.f;
            if (row0 + r < M) v = A[(size_t)(row0 + r) * K + k0 + c];
            As[c][r] = v;
        }
        for (int i = threadIdx.x; i < GBK * GBN; i += 256) {
            int r = i / GBN, c = i % GBN;
            float v = 0.f;
            if (col0 + c < Ncol) v = B[(size_t)(k0 + r) * Ncol + col0 + c];
            Bs[r][c] = v;
        }
        __syncthreads();
        #pragma unroll
        for (int k = 0; k < GBK; ++k) {
            float a[4], b[4];
            #pragma unroll
            for (int i = 0; i < 4; ++i) a[i] = As[k][ty * 4 + i];
            #pragma unroll
            for (int j = 0; j < 4; ++j) b[j] = Bs[k][tx * 4 + j];
            #pragma unroll
            for (int i = 0; i < 4; ++i)
                #pragma unroll
                for (int j = 0; j < 4; ++j)
                    acc[i][j] = fmaf(a[i], b[j], acc[i][j]);
        }
        __syncthreads();
    }
    #pragma unroll
    for (int i = 0; i < 4; ++i) {
        int r = row0 + ty * 4 + i;
        if (r >= M) continue;
        #pragma unroll
        for (int j = 0; j < 4; ++j) {
            int c = col0 + tx * 4 + j;
            if (c >= Ncol) continue;
            float v = acc[i][j] + (bias ? bias[c] : 0.f);
            if (act == 1) v = fmaxf(v, 0.f);
            C[(size_t)r * Ncol + c] = v;
        }
    }
}

// ---------------- pack per-layer node-level weights ----------------
// Wbig[128][768] = [ attW1 rows0:128 | attW1 rows128:256 | mlpW rows0:128 | gru_Whh ]
// bbig[768]      = [ attb1 | 0 | mlpb | gru_bhh ]
__global__ void pack_weights(const float* __restrict__ attW1,
                             const float* __restrict__ mlpW,
                             const float* __restrict__ whh,
                             const float* __restrict__ attb1,
                             const float* __restrict__ mlpb,
                             const float* __restrict__ bhh,
                             float* __restrict__ Wbig, float* __restrict__ bbig)
{
    int idx = blockIdx.x * blockDim.x + threadIdx.x;
    if (idx >= 128 * 768) return;
    int k = idx / 768, j = idx % 768;
    float v;
    if (j < 128)      v = attW1[k * 128 + j];
    else if (j < 256) v = attW1[(128 + k) * 128 + (j - 128)];
    else if (j < 384) v = mlpW[k * 128 + (j - 256)];
    else              v = whh[k * 384 + (j - 384)];
    Wbig[idx] = v;
    if (idx < 768) {
        float b;
        if (idx < 128)      b = attb1[idx];
        else if (idx < 256) b = 0.f;
        else if (idx < 384) b = mlpb[idx - 256];
        else                b = bhh[idx - 384];
        bbig[idx] = b;
    }
}

// ---------------- CSR build ----------------
__global__ void hist_dst_kernel(const int* __restrict__ ei, int* __restrict__ deg) {
    int e = blockIdx.x * blockDim.x + threadIdx.x;
    if (e < N_EDGES) atomicAdd(&deg[ei[N_EDGES + e]], 1);
}
__global__ void hist_batch_kernel(const int* __restrict__ batch, int* __restrict__ hist) {
    int n = blockIdx.x * blockDim.x + threadIdx.x;
    if (n < N_NODES) atomicAdd(&hist[batch[n]], 1);
}
__global__ __launch_bounds__(1024) void scan_excl_kernel(
    const int* __restrict__ in, int* __restrict__ out, int n)
{
    __shared__ int buf[1024];
    __shared__ int carry_s;
    if (threadIdx.x == 0) carry_s = 0;
    __syncthreads();
    for (int base = 0; base < n; base += 1024) {
        int i = base + threadIdx.x;
        int v = (i < n) ? in[i] : 0;
        __syncthreads();
        buf[threadIdx.x] = v;
        __syncthreads();
        for (int off = 1; off < 1024; off <<= 1) {
            int t = 0;
            if (threadIdx.x >= off) t = buf[threadIdx.x - off];
            __syncthreads();
            buf[threadIdx.x] += t;
            __syncthreads();
        }
        int carry = carry_s;
        __syncthreads();
        if (threadIdx.x == 0) carry_s = carry + buf[1023];
        if (i < n) out[i] = carry + buf[threadIdx.x] - v;
    }
    __syncthreads();
    if (threadIdx.x == 0) out[n] = carry_s;
}
__global__ void scatter_csr_kernel(const int* __restrict__ ei, const int* __restrict__ offs,
                                   int* __restrict__ cur, int* __restrict__ csr) {
    int e = blockIdx.x * blockDim.x + threadIdx.x;
    if (e >= N_EDGES) return;
    int d = ei[N_EDGES + e];
    int pos = offs[d] + atomicAdd(&cur[d], 1);
    csr[pos] = e;
}

// ---------------- edge attention scores ----------------
// t[0:128] = P[dst] + Q[src] + ea @ W1c  (P includes attb1); leaky 0.2; a = t.W2 + b2
// e_exp[e] = exp(a); s_sum[dst] += e_exp[e]   (no-max softmax: |a| is small)
__global__ __launch_bounds__(256) void edge_att_kernel(
    const float* __restrict__ pqmg, const int* __restrict__ ei,
    const float* __restrict__ ea, const float* __restrict__ w1c_g,
    const float* __restrict__ w2_g, const float* __restrict__ b2_g,
    float* __restrict__ e_exp, float* __restrict__ s_sum)
{
    __shared__ float w1c[16 * 128];
    __shared__ float w2[128];
    for (int i = threadIdx.x; i < 16 * 128; i += 256) w1c[i] = w1c_g[i];
    if (threadIdx.x < 128) w2[threadIdx.x] = w2_g[threadIdx.x];
    __syncthreads();
    const float b2 = b2_g[0];
    const int wave = threadIdx.x >> 6;
    const int lane = threadIdx.x & 63;
    #pragma unroll
    for (int it = 0; it < 8; ++it) {
        long e = (long)blockIdx.x * 32 + it * 4 + wave;
        if (e >= N_EDGES) break;
        int s = ei[e], d = ei[N_EDGES + e];
        const float* pd = pqmg + (size_t)d * 768;
        const float* ps = pqmg + (size_t)s * 768 + 128;
        float t0 = pd[lane] + ps[lane];
        float t1 = pd[lane + 64] + ps[lane + 64];
        const float* eap = ea + (size_t)e * 16;
        #pragma unroll
        for (int k = 0; k < 16; ++k) {
            float av = eap[k];
            t0 = fmaf(av, w1c[k * 128 + lane], t0);
            t1 = fmaf(av, w1c[k * 128 + lane + 64], t1);
        }
        t0 = (t0 > 0.f) ? t0 : 0.2f * t0;
        t1 = (t1 > 0.f) ? t1 : 0.2f * t1;
        float p = t0 * w2[lane] + t1 * w2[lane + 64];
        #pragma unroll
        for (int off = 32; off; off >>= 1) p += __shfl_xor(p, off);
        if (lane == 0) {
            float ex = expf(p + b2);
            e_exp[e] = ex;
            atomicAdd(&s_sum[d], ex);
        }
    }
}

// ---------------- aggregation: aggr[d] = sum_e alpha_e * relu(M[src]+ea@mlpW2) ----------------
__global__ __launch_bounds__(128) void aggregate_kernel(
    const float* __restrict__ pqmg, const int* __restrict__ ei,
    const float* __restrict__ ea, const float* __restrict__ mlpw2_g,
    const int* __restrict__ offs, const int* __restrict__ csr,
    const float* __restrict__ e_exp, const float* __restrict__ s_sum,
    float* __restrict__ aggr)
{
    __shared__ float w2[16 * 128];
    for (int i = threadIdx.x; i < 16 * 128; i += 128) w2[i] = mlpw2_g[i];
    __syncthreads();
    const int c = threadIdx.x;
    for (int r = 0; r < 4; ++r) {
        int d = blockIdx.x * 4 + r;
        if (d >= N_NODES) break;
        float invs = 1.f / (s_sum[d] + 1e-16f);
        float acc = 0.f;
        int b = offs[d], en = offs[d + 1];
        for (int i = b; i < en; ++i) {
            int e = csr[i];
            int s = ei[e];
            float alpha = e_exp[e] * invs;
            float m = pqmg[(size_t)s * 768 + 256 + c];
            const float* eap = ea + (size_t)e * 16;
            #pragma unroll
            for (int k = 0; k < 16; ++k) m = fmaf(eap[k], w2[k * 128 + c], m);
            acc = fmaf(alpha, fmaxf(m, 0.f), acc);
        }
        aggr[(size_t)d * 128 + c] = acc;
    }
}

// ---------------- GRU elementwise ----------------
__global__ void gru_elem_kernel(const float* __restrict__ gi,
                                const float* __restrict__ ghbase, int gh_stride, int gh_off,
                                const float* __restrict__ hold, float* __restrict__ hnew,
                                int rows)
{
    int idx = blockIdx.x * blockDim.x + threadIdx.x;
    if (idx >= rows * H) return;
    int r = idx >> 7, c = idx & 127;
    const float* gh = ghbase + (size_t)r * gh_stride + gh_off;
    float ir = gi[(size_t)r * 384 + c];
    float iz = gi[(size_t)r * 384 + 128 + c];
    float in = gi[(size_t)r * 384 + 256 + c];
    float hr = gh[c], hz = gh[128 + c], hn = gh[256 + c];
    float rg = 1.f / (1.f + expf(-(ir + hr)));
    float zg = 1.f / (1.f + expf(-(iz + hz)));
    float ng = tanhf(in + rg * hn);
    float hv = hold[idx];
    hnew[idx] = (1.f - zg) * ng + zg * hv;
}

// ---------------- graph pooling ----------------
__global__ __launch_bounds__(128) void graph_pool_sum(
    const float* __restrict__ h, const int* __restrict__ goffs, float* __restrict__ g0)
{
    int g = blockIdx.x, c = threadIdx.x;
    int b = goffs[g], e2 = goffs[g + 1];
    float acc = 0.f;
    for (int i = b; i < e2; ++i) acc += h[(size_t)i * 128 + c];
    g0[(size_t)g * 128 + c] = acc;
}

// node scores: s = tanh(h@W1+b1)@W2 + b2 ; es=exp(s); gsum[batch] += es (8 nodes/block)
__global__ __launch_bounds__(128) void node_score_kernel(
    const float* __restrict__ h, const float* __restrict__ W1,
    const float* __restrict__ b1, const float* __restrict__ W2,
    const float* __restrict__ b2, const int* __restrict__ batch,
    float* __restrict__ es, float* __restrict__ gsum)
{
    __shared__ float hrow[8][128];
    __shared__ float red[8][128];
    int base = blockIdx.x * 8;
    int c = threadIdx.x;
    #pragma unroll
    for (int r = 0; r < 8; ++r) {
        int nid = base + r;
        hrow[r][c] = (nid < N_NODES) ? h[(size_t)nid * 128 + c] : 0.f;
    }
    __syncthreads();
    float acc[8];
    float bb = b1[c];
    #pragma unroll
    for (int r = 0; r < 8; ++r) acc[r] = bb;
    for (int k = 0; k < 128; ++k) {
        float w = W1[k * 128 + c];
        #pragma unroll
        for (int r = 0; r < 8; ++r) acc[r] = fmaf(hrow[r][k], w, acc[r]);
    }
    float w2 = W2[c];
    #pragma unroll
    for (int r = 0; r < 8; ++r) red[r][c] = tanhf(acc[r]) * w2;
    __syncthreads();
    for (int off = 64; off; off >>= 1) {
        if (c < off) {
            #pragma unroll
            for (int r = 0; r < 8; ++r) red[r][c] += red[r][c + off];
        }
        __syncthreads();
    }
    if (c < 8) {
        int nid = base + c;
        if (nid < N_NODES) {
            float s = red[c][0] + b2[0];
            float ex = expf(s);
            es[nid] = ex;
            atomicAdd(&gsum[batch[nid]], ex);
        }
    }
}

__global__ __launch_bounds__(128) void graph_ctx_kernel(
    const float* __restrict__ h, const int* __restrict__ goffs,
    const float* __restrict__ es, const float* __restrict__ gsum,
    float* __restrict__ ctx)
{
    int g = blockIdx.x, c = threadIdx.x;
    float invs = 1.f / (gsum[g] + 1e-16f);
    int b = goffs[g], e2 = goffs[g + 1];
    float acc = 0.f;
    for (int i = b; i < e2; ++i) acc = fmaf(es[i] * invs, h[(size_t)i * 128 + c], acc);
    ctx[(size_t)g * 128 + c] = acc;
}

extern "C" void kernel_launch(void* const* d_in, const int* in_sizes, int n_in,
                              void* d_out, int out_size, void* d_ws, size_t ws_size,
                              hipStream_t stream) {
    const float* x      = (const float*)d_in[0];
    const int*   ei     = (const int*)d_in[1];
    const float* ea     = (const float*)d_in[2];
    const int*   batch  = (const int*)d_in[3];
    const float* embW   = (const float*)d_in[4];
    const float* embB   = (const float*)d_in[5];
    const float* attW1  = (const float*)d_in[6];
    const float* attb1  = (const float*)d_in[7];
    const float* attW2  = (const float*)d_in[8];
    const float* attb2  = (const float*)d_in[9];
    const float* mlpW   = (const float*)d_in[10];
    const float* mlpb   = (const float*)d_in[11];
    const float* gWih   = (const float*)d_in[12];
    const float* gWhh   = (const float*)d_in[13];
    const float* gbih   = (const float*)d_in[14];
    const float* gbhh   = (const float*)d_in[15];
    const float* gattW1 = (const float*)d_in[16];
    const float* gattb1 = (const float*)d_in[17];
    const float* gattW2 = (const float*)d_in[18];
    const float* gattb2 = (const float*)d_in[19];
    const float* ggWih  = (const float*)d_in[20];
    const float* ggWhh  = (const float*)d_in[21];
    const float* ggbih  = (const float*)d_in[22];
    const float* ggbhh  = (const float*)d_in[23];
    float* out = (float*)d_out;

    void* basep = nullptr;
    hipGetSymbolAddress(&basep, HIP_SYMBOL(g_afp_ws));
    char* base = (char*)basep;
    float* h0    = (float*)(base + OFF_H0);
    float* h1    = (float*)(base + OFF_H1);
    float* pqmg  = (float*)(base + OFF_PQMG);
    float* gi    = (float*)(base + OFF_GI);
    float* aggr  = (float*)(base + OFF_AGGR);
    float* eexp  = (float*)(base + OFF_EEXP);
    float* ssum  = (float*)(base + OFF_SSUM);
    float* es    = (float*)(base + OFF_ES);
    float* wbig  = (float*)(base + OFF_WBIG);
    float* bbig  = (float*)(base + OFF_BBIG);
    float* g0b   = (float*)(base + OFF_G0);
    float* gAb   = (float*)(base + OFF_GA);
    float* ctx   = (float*)(base + OFF_CTX);
    float* gictx = (float*)(base + OFF_GICTX);
    float* ghb   = (float*)(base + OFF_GHB);
    float* gsum  = (float*)(base + OFF_GSUM);
    int*   deg   = (int*)(base + OFF_DEG);
    int*   offs  = (int*)(base + OFF_OFFS);
    int*   cur   = (int*)(base + OFF_CUR);
    int*   csr   = (int*)(base + OFF_CSR);
    int*   ghist = (int*)(base + OFF_GHIST);
    int*   goffs = (int*)(base + OFF_GOFFS);

    hipMemsetAsync(deg, 0, SZ_NF, stream);
    hipMemsetAsync(cur, 0, SZ_NF, stream);
    hipMemsetAsync(ghist, 0, SZ_GF, stream);
    hipMemsetAsync(gsum, 0, SZ_GF, stream);

    // CSR by dst + graph offsets (batch is sorted)
    hist_dst_kernel<<<(N_EDGES + 255) / 256, 256, 0, stream>>>(ei, deg);
    scan_excl_kernel<<<1, 1024, 0, stream>>>(deg, offs, N_NODES);
    scatter_csr_kernel<<<(N_EDGES + 255) / 256, 256, 0, stream>>>(ei, offs, cur, csr);
    hist_batch_kernel<<<(N_NODES + 255) / 256, 256, 0, stream>>>(batch, ghist);
    scan_excl_kernel<<<1, 1024, 0, stream>>>(ghist, goffs, N_GRAPHS);

    // embedding: h0 = relu(x @ embW + embB)
    {
        dim3 g((N_NODES + GBM - 1) / GBM, H / GBN);
        gemm_f32<<<g, 256, 0, stream>>>(x, embW, embB, h0, N_NODES, FN, H, 1);
    }

    float* hcur = h0;
    float* hnext = h1;
    for (int l = 0; l < NL; ++l) {
        pack_weights<<<(128 * 768 + 255) / 256, 256, 0, stream>>>(
            attW1 + (size_t)l * 272 * 128, mlpW + (size_t)l * 144 * 128,
            gWhh + (size_t)l * 128 * 384, attb1 + l * 128, mlpb + l * 128,
            gbhh + l * 384, wbig, bbig);
        {
            dim3 g((N_NODES + GBM - 1) / GBM, 768 / GBN);
            gemm_f32<<<g, 256, 0, stream>>>(hcur, wbig, bbig, pqmg, N_NODES, H, 768, 0);
        }
        hipMemsetAsync(ssum, 0, SZ_NF, stream);
        edge_att_kernel<<<(N_EDGES + 31) / 32, 256, 0, stream>>>(
            pqmg, ei, ea, attW1 + (size_t)l * 272 * 128 + 256 * 128,
            attW2 + (size_t)l * 128, attb2 + l, eexp, ssum);
        aggregate_kernel<<<(N_NODES + 3) / 4, 128, 0, stream>>>(
            pqmg, ei, ea, mlpW + (size_t)l * 144 * 128 + 128 * 128,
            offs, csr, eexp, ssum, aggr);
        {
            dim3 g((N_NODES + GBM - 1) / GBM, 384 / GBN);
            gemm_f32<<<g, 256, 0, stream>>>(aggr, gWih + (size_t)l * 128 * 384,
                                            gbih + l * 384, gi, N_NODES, H, 384, 0);
        }
        gru_elem_kernel<<<((size_t)N_NODES * H + 255) / 256, 256, 0, stream>>>(
            gi, pqmg, 768, 384, hcur, hnext, N_NODES);
        float* t = hcur; hcur = hnext; hnext = t;
    }

    // readout: ctx is identical across T (h fixed) -> compute once
    graph_pool_sum<<<N_GRAPHS, 128, 0, stream>>>(hcur, goffs, g0b);
    node_score_kernel<<<(N_NODES + 7) / 8, 128, 0, stream>>>(
        hcur, gattW1, gattb1, gattW2, gattb2, batch, es, gsum);
    graph_ctx_kernel<<<N_GRAPHS, 128, 0, stream>>>(hcur, goffs, es, gsum, ctx);

    dim3 gg((N_GRAPHS + GBM - 1) / GBM, 384 / GBN);
    gemm_f32<<<gg, 256, 0, stream>>>(ctx, ggWih, ggbih, gictx, N_GRAPHS, H, 384, 0);
    // T iter 1
    gemm_f32<<<gg, 256, 0, stream>>>(g0b, ggWhh, ggbhh, ghb, N_GRAPHS, H, 384, 0);
    gru_elem_kernel<<<((size_t)N_GRAPHS * H + 255) / 256, 256, 0, stream>>>(
        gictx, ghb, 384, 0, g0b, gAb, N_GRAPHS);
    // T iter 2 -> d_out
    gemm_f32<<<gg, 256, 0, stream>>>(gAb, ggWhh, ggbhh, ghb, N_GRAPHS, H, 384, 0);
    gru_elem_kernel<<<((size_t)N_GRAPHS * H + 255) / 256, 256, 0, stream>>>(
        gictx, ghb, 384, 0, gAb, out, N_GRAPHS);
}

// Round 2
// 1651.939 us; speedup vs baseline: 1.0863x; 1.0863x over previous
//
#include <hip/hip_runtime.h>
#include <hip/hip_bf16.h>
#include <math.h>

#define N_NODES 50000
#define N_EDGES 640000
#define N_GRAPHS 2000
#define FN 64
#define FE 16
#define H 128
#define NL 2

// ---------------- static workspace ----------------
static constexpr size_t AL = 256;
static constexpr size_t alup(size_t x) { return (x + AL - 1) & ~(AL - 1); }

static constexpr size_t SZ_H      = (size_t)N_NODES * H * 4;        // 25.6 MB
static constexpr size_t SZ_PQMB   = (size_t)N_NODES * 384 * 2;      // 38.4 MB bf16
static constexpr size_t SZ_GH     = (size_t)N_NODES * 384 * 4;      // 76.8 MB
static constexpr size_t SZ_GI     = (size_t)N_NODES * 384 * 4;      // 76.8 MB
static constexpr size_t SZ_NF     = (size_t)N_NODES * 4;
static constexpr size_t SZ_WBIG   = (size_t)128 * 768 * 4;
static constexpr size_t SZ_BBIG   = (size_t)768 * 4;
static constexpr size_t SZ_G128   = (size_t)N_GRAPHS * 128 * 4;
static constexpr size_t SZ_G384   = (size_t)N_GRAPHS * 384 * 4;
static constexpr size_t SZ_GF     = (size_t)N_GRAPHS * 4;
static constexpr size_t SZ_CSR    = (size_t)N_EDGES * 4;

static constexpr size_t OFF_H0    = 0;
static constexpr size_t OFF_H1    = alup(OFF_H0 + SZ_H);
static constexpr size_t OFF_PQMB  = alup(OFF_H1 + SZ_H);
static constexpr size_t OFF_GH    = alup(OFF_PQMB + SZ_PQMB);
static constexpr size_t OFF_GI    = alup(OFF_GH + SZ_GH);
static constexpr size_t OFF_AGGR  = alup(OFF_GI + SZ_GI);
static constexpr size_t OFF_ES    = alup(OFF_AGGR + SZ_H);
static constexpr size_t OFF_WBIG  = alup(OFF_ES + SZ_NF);
static constexpr size_t OFF_BBIG  = alup(OFF_WBIG + SZ_WBIG);
static constexpr size_t OFF_G0    = alup(OFF_BBIG + SZ_BBIG);
static constexpr size_t OFF_GA    = alup(OFF_G0 + SZ_G128);
static constexpr size_t OFF_CTX   = alup(OFF_GA + SZ_G128);
static constexpr size_t OFF_GICTX = alup(OFF_CTX + SZ_G128);
static constexpr size_t OFF_GHB   = alup(OFF_GICTX + SZ_G384);
static constexpr size_t OFF_GSUM  = alup(OFF_GHB + SZ_G384);
static constexpr size_t OFF_DEG   = alup(OFF_GSUM + SZ_GF);
static constexpr size_t OFF_OFFS  = alup(OFF_DEG + SZ_NF);
static constexpr size_t OFF_CUR   = alup(OFF_OFFS + SZ_NF + 4);
static constexpr size_t OFF_CSR   = alup(OFF_CUR + SZ_NF);
static constexpr size_t OFF_GHIST = alup(OFF_CSR + SZ_CSR);
static constexpr size_t OFF_GOFFS = alup(OFF_GHIST + SZ_GF);
static constexpr size_t TOTAL_WS  = alup(OFF_GOFFS + SZ_GF + 4);

__device__ unsigned char g_afp_ws[TOTAL_WS];

__device__ inline float bf2f(unsigned short u) {
    unsigned int x = ((unsigned int)u) << 16;
    return __uint_as_float(x);
}

// ---------------- generic tiled f32 GEMM: C = act(A@B + bias) ----------------
// A [M,K] row-major, B [K,Ncol] row-major.
// mode 0: C[r*Ncol+c] = act(v)
// mode 2: (Ncol==768) cols<384 -> Cb[r*384+c] = bf16(v); cols>=384 -> C[r*384+c-384] = v
#define GBM 64
#define GBN 64
#define GBK 32
__global__ __launch_bounds__(256) void gemm_f32(
    const float* __restrict__ A, const float* __restrict__ B,
    const float* __restrict__ bias, float* __restrict__ C,
    __hip_bfloat16* __restrict__ Cb,
    int M, int K, int Ncol, int act, int mode)
{
    __shared__ float As[GBK][GBM + 4];
    __shared__ float Bs[GBK][GBN + 4];
    const int tx = threadIdx.x & 15;
    const int ty = threadIdx.x >> 4;
    const int row0 = blockIdx.x * GBM;
    const int col0 = blockIdx.y * GBN;
    float acc[4][4] = {};
    for (int k0 = 0; k0 < K; k0 += GBK) {
        for (int i = threadIdx.x; i < GBM * GBK; i += 256) {
            int r = i / GBK, c = i % GBK;
            float v = 0.f;
            if (row0 + r < M) v = A[(size_t)(row0 + r) * K + k0 + c];
            As[c][r] = v;
        }
        for (int i = threadIdx.x; i < GBK * GBN; i += 256) {
            int r = i / GBN, c = i % GBN;
            float v = 0.f;
            if (col0 + c < Ncol) v = B[(size_t)(k0 + r) * Ncol + col0 + c];
            Bs[r][c] = v;
        }
        __syncthreads();
        #pragma unroll
        for (int k = 0; k < GBK; ++k) {
            float a[4], b[4];
            #pragma unroll
            for (int i = 0; i < 4; ++i) a[i] = As[k][ty * 4 + i];
            #pragma unroll
            for (int j = 0; j < 4; ++j) b[j] = Bs[k][tx * 4 + j];
            #pragma unroll
            for (int i = 0; i < 4; ++i)
                #pragma unroll
                for (int j = 0; j < 4; ++j)
                    acc[i][j] = fmaf(a[i], b[j], acc[i][j]);
        }
        __syncthreads();
    }
    #pragma unroll
    for (int i = 0; i < 4; ++i) {
        int r = row0 + ty * 4 + i;
        if (r >= M) continue;
        #pragma unroll
        for (int j = 0; j < 4; ++j) {
            int c = col0 + tx * 4 + j;
            if (c >= Ncol) continue;
            float v = acc[i][j] + (bias ? bias[c] : 0.f);
            if (act == 1) v = fmaxf(v, 0.f);
            if (mode == 0) {
                C[(size_t)r * Ncol + c] = v;
            } else { // mode 2
                if (c < 384) Cb[(size_t)r * 384 + c] = __float2bfloat16(v);
                else         C[(size_t)r * 384 + (c - 384)] = v;
            }
        }
    }
}

// ---------------- pack per-layer node-level weights ----------------
// Wbig[128][768] = [ attW1 rows0:128 | attW1 rows128:256 | mlpW rows0:128 | gru_Whh ]
// bbig[768]      = [ attb1 | 0 | mlpb | gru_bhh ]
__global__ void pack_weights(const float* __restrict__ attW1,
                             const float* __restrict__ mlpW,
                             const float* __restrict__ whh,
                             const float* __restrict__ attb1,
                             const float* __restrict__ mlpb,
                             const float* __restrict__ bhh,
                             float* __restrict__ Wbig, float* __restrict__ bbig)
{
    int idx = blockIdx.x * blockDim.x + threadIdx.x;
    if (idx >= 128 * 768) return;
    int k = idx / 768, j = idx % 768;
    float v;
    if (j < 128)      v = attW1[k * 128 + j];
    else if (j < 256) v = attW1[(128 + k) * 128 + (j - 128)];
    else if (j < 384) v = mlpW[k * 128 + (j - 256)];
    else              v = whh[k * 384 + (j - 384)];
    Wbig[idx] = v;
    if (idx < 768) {
        float b;
        if (idx < 128)      b = attb1[idx];
        else if (idx < 256) b = 0.f;
        else if (idx < 384) b = mlpb[idx - 256];
        else                b = bhh[idx - 384];
        bbig[idx] = b;
    }
}

// ---------------- CSR build ----------------
__global__ void hist_dst_kernel(const int* __restrict__ ei, int* __restrict__ deg) {
    int e = blockIdx.x * blockDim.x + threadIdx.x;
    if (e < N_EDGES) atomicAdd(&deg[ei[N_EDGES + e]], 1);
}
__global__ void hist_batch_kernel(const int* __restrict__ batch, int* __restrict__ hist) {
    int n = blockIdx.x * blockDim.x + threadIdx.x;
    if (n < N_NODES) atomicAdd(&hist[batch[n]], 1);
}
__global__ __launch_bounds__(1024) void scan_excl_kernel(
    const int* __restrict__ in, int* __restrict__ out, int n)
{
    __shared__ int buf[1024];
    __shared__ int carry_s;
    if (threadIdx.x == 0) carry_s = 0;
    __syncthreads();
    for (int base = 0; base < n; base += 1024) {
        int i = base + threadIdx.x;
        int v = (i < n) ? in[i] : 0;
        __syncthreads();
        buf[threadIdx.x] = v;
        __syncthreads();
        for (int off = 1; off < 1024; off <<= 1) {
            int t = 0;
            if (threadIdx.x >= off) t = buf[threadIdx.x - off];
            __syncthreads();
            buf[threadIdx.x] += t;
            __syncthreads();
        }
        int carry = carry_s;
        __syncthreads();
        if (threadIdx.x == 0) carry_s = carry + buf[1023];
        if (i < n) out[i] = carry + buf[threadIdx.x] - v;
    }
    __syncthreads();
    if (threadIdx.x == 0) out[n] = carry_s;
}
__global__ void scatter_csr_kernel(const int* __restrict__ ei, const int* __restrict__ offs,
                                   int* __restrict__ cur, int* __restrict__ csr) {
    int e = blockIdx.x * blockDim.x + threadIdx.x;
    if (e >= N_EDGES) return;
    int d = ei[N_EDGES + e];
    int pos = offs[d] + atomicAdd(&cur[d], 1);
    csr[pos] = e;
}

// ---------------- fused edge attention + aggregation (wave per dst) ----------------
// pqm [N,384] bf16: P(+attb1) | Q | M(+mlpb)
// per dst: a_e = leaky(P[d]+Q[s]+ea@W1c).w2 + b2 ; ex=exp(a) (no-max softmax, |a| small)
// aggr[d] = (sum_e ex * relu(M[s]+ea@mlpW2)) / (sum_e ex + 1e-16)
__global__ __launch_bounds__(256) void edge_fused_kernel(
    const __hip_bfloat16* __restrict__ pqm,
    const int* __restrict__ ei, const float* __restrict__ ea,
    const float* __restrict__ w1c_g, const float* __restrict__ w2_g,
    const float* __restrict__ b2_g, const float* __restrict__ mlpw2_g,
    const int* __restrict__ offs, const int* __restrict__ csr,
    float* __restrict__ aggr)
{
    const int wv = threadIdx.x >> 6, lane = threadIdx.x & 63;
    const int c0 = lane * 2;
    // per-lane weight columns in registers
    float w1r[16][2], wmr[16][2];
    #pragma unroll
    for (int k = 0; k < 16; ++k) {
        w1r[k][0] = w1c_g[k * 128 + c0];
        w1r[k][1] = w1c_g[k * 128 + c0 + 1];
        wmr[k][0] = mlpw2_g[k * 128 + c0];
        wmr[k][1] = mlpw2_g[k * 128 + c0 + 1];
    }
    const float w20 = w2_g[c0], w21 = w2_g[c0 + 1];
    const float b2 = b2_g[0];
    const int d = blockIdx.x * 4 + wv;
    if (d >= N_NODES) return;
    const ushort2 pu = *(const ushort2*)((const unsigned short*)pqm + (size_t)d * 384 + c0);
    const float p0 = bf2f(pu.x), p1 = bf2f(pu.y);
    float acc0 = 0.f, acc1 = 0.f, ssum = 0.f;
    const int b = offs[d], en = offs[d + 1];
    for (int i = b; i < en; ++i) {
        const int e = csr[i];
        const int s = ei[e];
        const unsigned short* ps = (const unsigned short*)pqm + (size_t)s * 384;
        const ushort2 qu = *(const ushort2*)(ps + 128 + c0);
        const ushort2 mu = *(const ushort2*)(ps + 256 + c0);
        // ea broadcast loads (same addr all lanes)
        const float4* eap = (const float4*)(ea + (size_t)e * 16);
        float ear[16];
        {
            float4 v0 = eap[0], v1 = eap[1], v2 = eap[2], v3 = eap[3];
            ear[0]=v0.x; ear[1]=v0.y; ear[2]=v0.z; ear[3]=v0.w;
            ear[4]=v1.x; ear[5]=v1.y; ear[6]=v1.z; ear[7]=v1.w;
            ear[8]=v2.x; ear[9]=v2.y; ear[10]=v2.z; ear[11]=v2.w;
            ear[12]=v3.x; ear[13]=v3.y; ear[14]=v3.z; ear[15]=v3.w;
        }
        float t0 = p0 + bf2f(qu.x), t1 = p1 + bf2f(qu.y);
        float m0 = bf2f(mu.x), m1 = bf2f(mu.y);
        #pragma unroll
        for (int k = 0; k < 16; ++k) {
            t0 = fmaf(ear[k], w1r[k][0], t0);
            t1 = fmaf(ear[k], w1r[k][1], t1);
            m0 = fmaf(ear[k], wmr[k][0], m0);
            m1 = fmaf(ear[k], wmr[k][1], m1);
        }
        t0 = (t0 > 0.f) ? t0 : 0.2f * t0;
        t1 = (t1 > 0.f) ? t1 : 0.2f * t1;
        float sp = t0 * w20 + t1 * w21;
        #pragma unroll
        for (int off = 32; off; off >>= 1) sp += __shfl_xor(sp, off);
        const float ex = expf(sp + b2);
        acc0 = fmaf(ex, fmaxf(m0, 0.f), acc0);
        acc1 = fmaf(ex, fmaxf(m1, 0.f), acc1);
        ssum += ex;
    }
    const float inv = 1.f / (ssum + 1e-16f);
    aggr[(size_t)d * 128 + c0]     = acc0 * inv;
    aggr[(size_t)d * 128 + c0 + 1] = acc1 * inv;
}

// ---------------- GRU elementwise ----------------
__global__ void gru_elem_kernel(const float* __restrict__ gi,
                                const float* __restrict__ gh,
                                const float* __restrict__ hold, float* __restrict__ hnew,
                                int rows)
{
    int idx = blockIdx.x * blockDim.x + threadIdx.x;
    if (idx >= rows * H) return;
    int r = idx >> 7, c = idx & 127;
    float ir = gi[(size_t)r * 384 + c];
    float iz = gi[(size_t)r * 384 + 128 + c];
    float in = gi[(size_t)r * 384 + 256 + c];
    float hr = gh[(size_t)r * 384 + c];
    float hz = gh[(size_t)r * 384 + 128 + c];
    float hn = gh[(size_t)r * 384 + 256 + c];
    float rg = 1.f / (1.f + expf(-(ir + hr)));
    float zg = 1.f / (1.f + expf(-(iz + hz)));
    float ng = tanhf(in + rg * hn);
    float hv = hold[idx];
    hnew[idx] = (1.f - zg) * ng + zg * hv;
}

// ---------------- graph pooling ----------------
__global__ __launch_bounds__(128) void graph_pool_sum(
    const float* __restrict__ h, const int* __restrict__ goffs, float* __restrict__ g0)
{
    int g = blockIdx.x, c = threadIdx.x;
    int b = goffs[g], e2 = goffs[g + 1];
    float acc = 0.f;
    for (int i = b; i < e2; ++i) acc += h[(size_t)i * 128 + c];
    g0[(size_t)g * 128 + c] = acc;
}

// node scores: s = tanh(h@W1+b1)@W2 + b2 ; es=exp(s); gsum[batch] += es (8 nodes/block)
__global__ __launch_bounds__(128) void node_score_kernel(
    const float* __restrict__ h, const float* __restrict__ W1,
    const float* __restrict__ b1, const float* __restrict__ W2,
    const float* __restrict__ b2, const int* __restrict__ batch,
    float* __restrict__ es, float* __restrict__ gsum)
{
    __shared__ float hrow[8][128];
    __shared__ float red[8][128];
    int base = blockIdx.x * 8;
    int c = threadIdx.x;
    #pragma unroll
    for (int r = 0; r < 8; ++r) {
        int nid = base + r;
        hrow[r][c] = (nid < N_NODES) ? h[(size_t)nid * 128 + c] : 0.f;
    }
    __syncthreads();
    float acc[8];
    float bb = b1[c];
    #pragma unroll
    for (int r = 0; r < 8; ++r) acc[r] = bb;
    for (int k = 0; k < 128; ++k) {
        float w = W1[k * 128 + c];
        #pragma unroll
        for (int r = 0; r < 8; ++r) acc[r] = fmaf(hrow[r][k], w, acc[r]);
    }
    float w2 = W2[c];
    #pragma unroll
    for (int r = 0; r < 8; ++r) red[r][c] = tanhf(acc[r]) * w2;
    __syncthreads();
    for (int off = 64; off; off >>= 1) {
        if (c < off) {
            #pragma unroll
            for (int r = 0; r < 8; ++r) red[r][c] += red[r][c + off];
        }
        __syncthreads();
    }
    if (c < 8) {
        int nid = base + c;
        if (nid < N_NODES) {
            float s = red[c][0] + b2[0];
            float ex = expf(s);
            es[nid] = ex;
            atomicAdd(&gsum[batch[nid]], ex);
        }
    }
}

__global__ __launch_bounds__(128) void graph_ctx_kernel(
    const float* __restrict__ h, const int* __restrict__ goffs,
    const float* __restrict__ es, const float* __restrict__ gsum,
    float* __restrict__ ctx)
{
    int g = blockIdx.x, c = threadIdx.x;
    float invs = 1.f / (gsum[g] + 1e-16f);
    int b = goffs[g], e2 = goffs[g + 1];
    float acc = 0.f;
    for (int i = b; i < e2; ++i) acc = fmaf(es[i] * invs, h[(size_t)i * 128 + c], acc);
    ctx[(size_t)g * 128 + c] = acc;
}

extern "C" void kernel_launch(void* const* d_in, const int* in_sizes, int n_in,
                              void* d_out, int out_size, void* d_ws, size_t ws_size,
                              hipStream_t stream) {
    const float* x      = (const float*)d_in[0];
    const int*   ei     = (const int*)d_in[1];
    const float* ea     = (const float*)d_in[2];
    const int*   batch  = (const int*)d_in[3];
    const float* embW   = (const float*)d_in[4];
    const float* embB   = (const float*)d_in[5];
    const float* attW1  = (const float*)d_in[6];
    const float* attb1  = (const float*)d_in[7];
    const float* attW2  = (const float*)d_in[8];
    const float* attb2  = (const float*)d_in[9];
    const float* mlpW   = (const float*)d_in[10];
    const float* mlpb   = (const float*)d_in[11];
    const float* gWih   = (const float*)d_in[12];
    const float* gWhh   = (const float*)d_in[13];
    const float* gbih   = (const float*)d_in[14];
    const float* gbhh   = (const float*)d_in[15];
    const float* gattW1 = (const float*)d_in[16];
    const float* gattb1 = (const float*)d_in[17];
    const float* gattW2 = (const float*)d_in[18];
    const float* gattb2 = (const float*)d_in[19];
    const float* ggWih  = (const float*)d_in[20];
    const float* ggWhh  = (const float*)d_in[21];
    const float* ggbih  = (const float*)d_in[22];
    const float* ggbhh  = (const float*)d_in[23];
    float* out = (float*)d_out;

    void* basep = nullptr;
    hipGetSymbolAddress(&basep, HIP_SYMBOL(g_afp_ws));
    char* base = (char*)basep;
    float* h0    = (float*)(base + OFF_H0);
    float* h1    = (float*)(base + OFF_H1);
    __hip_bfloat16* pqmb = (__hip_bfloat16*)(base + OFF_PQMB);
    float* gh    = (float*)(base + OFF_GH);
    float* gi    = (float*)(base + OFF_GI);
    float* aggr  = (float*)(base + OFF_AGGR);
    float* es    = (float*)(base + OFF_ES);
    float* wbig  = (float*)(base + OFF_WBIG);
    float* bbig  = (float*)(base + OFF_BBIG);
    float* g0b   = (float*)(base + OFF_G0);
    float* gAb   = (float*)(base + OFF_GA);
    float* ctx   = (float*)(base + OFF_CTX);
    float* gictx = (float*)(base + OFF_GICTX);
    float* ghb   = (float*)(base + OFF_GHB);
    float* gsum  = (float*)(base + OFF_GSUM);
    int*   deg   = (int*)(base + OFF_DEG);
    int*   offs  = (int*)(base + OFF_OFFS);
    int*   cur   = (int*)(base + OFF_CUR);
    int*   csr   = (int*)(base + OFF_CSR);
    int*   ghist = (int*)(base + OFF_GHIST);
    int*   goffs = (int*)(base + OFF_GOFFS);

    hipMemsetAsync(deg, 0, SZ_NF, stream);
    hipMemsetAsync(cur, 0, SZ_NF, stream);
    hipMemsetAsync(ghist, 0, SZ_GF, stream);
    hipMemsetAsync(gsum, 0, SZ_GF, stream);

    // CSR by dst + graph offsets (batch is sorted)
    hist_dst_kernel<<<(N_EDGES + 255) / 256, 256, 0, stream>>>(ei, deg);
    scan_excl_kernel<<<1, 1024, 0, stream>>>(deg, offs, N_NODES);
    scatter_csr_kernel<<<(N_EDGES + 255) / 256, 256, 0, stream>>>(ei, offs, cur, csr);
    hist_batch_kernel<<<(N_NODES + 255) / 256, 256, 0, stream>>>(batch, ghist);
    scan_excl_kernel<<<1, 1024, 0, stream>>>(ghist, goffs, N_GRAPHS);

    // embedding: h0 = relu(x @ embW + embB)
    {
        dim3 g((N_NODES + GBM - 1) / GBM, H / GBN);
        gemm_f32<<<g, 256, 0, stream>>>(x, embW, embB, h0, nullptr, N_NODES, FN, H, 1, 0);
    }

    float* hcur = h0;
    float* hnext = h1;
    for (int l = 0; l < NL; ++l) {
        pack_weights<<<(128 * 768 + 255) / 256, 256, 0, stream>>>(
            attW1 + (size_t)l * 272 * 128, mlpW + (size_t)l * 144 * 128,
            gWhh + (size_t)l * 128 * 384, attb1 + l * 128, mlpb + l * 128,
            gbhh + l * 384, wbig, bbig);
        {
            // pqmb (bf16, cols 0..383) + gh (f32, cols 384..767)
            dim3 g((N_NODES + GBM - 1) / GBM, 768 / GBN);
            gemm_f32<<<g, 256, 0, stream>>>(hcur, wbig, bbig, gh, pqmb,
                                            N_NODES, H, 768, 0, 2);
        }
        edge_fused_kernel<<<(N_NODES + 3) / 4, 256, 0, stream>>>(
            pqmb, ei, ea, attW1 + (size_t)l * 272 * 128 + 256 * 128,
            attW2 + (size_t)l * 128, attb2 + l,
            mlpW + (size_t)l * 144 * 128 + 128 * 128,
            offs, csr, aggr);
        {
            dim3 g((N_NODES + GBM - 1) / GBM, 384 / GBN);
            gemm_f32<<<g, 256, 0, stream>>>(aggr, gWih + (size_t)l * 128 * 384,
                                            gbih + l * 384, gi, nullptr,
                                            N_NODES, H, 384, 0, 0);
        }
        gru_elem_kernel<<<((size_t)N_NODES * H + 255) / 256, 256, 0, stream>>>(
            gi, gh, hcur, hnext, N_NODES);
        float* t = hcur; hcur = hnext; hnext = t;
    }

    // readout: ctx is identical across T (h fixed) -> compute once
    graph_pool_sum<<<N_GRAPHS, 128, 0, stream>>>(hcur, goffs, g0b);
    node_score_kernel<<<(N_NODES + 7) / 8, 128, 0, stream>>>(
        hcur, gattW1, gattb1, gattW2, gattb2, batch, es, gsum);
    graph_ctx_kernel<<<N_GRAPHS, 128, 0, stream>>>(hcur, goffs, es, gsum, ctx);

    dim3 gg((N_GRAPHS + GBM - 1) / GBM, 384 / GBN);
    gemm_f32<<<gg, 256, 0, stream>>>(ctx, ggWih, ggbih, gictx, nullptr,
                                     N_GRAPHS, H, 384, 0, 0);
    // T iter 1
    gemm_f32<<<gg, 256, 0, stream>>>(g0b, ggWhh, ggbhh, ghb, nullptr,
                                     N_GRAPHS, H, 384, 0, 0);
    gru_elem_kernel<<<((size_t)N_GRAPHS * H + 255) / 256, 256, 0, stream>>>(
        gictx, ghb, g0b, gAb, N_GRAPHS);
    // T iter 2 -> d_out
    gemm_f32<<<gg, 256, 0, stream>>>(gAb, ggWhh, ggbhh, ghb, nullptr,
                                     N_GRAPHS, H, 384, 0, 0);
    gru_elem_kernel<<<((size_t)N_GRAPHS * H + 255) / 256, 256, 0, stream>>>(
        gictx, ghb, gAb, out, N_GRAPHS);
}

// Round 5
// 1553.780 us; speedup vs baseline: 1.1549x; 1.0632x over previous
//
#include <hip/hip_runtime.h>
#include <hip/hip_bf16.h>
#include <math.h>

#define N_NODES 50000
#define N_EDGES 640000
#define N_GRAPHS 2000
#define FN 64
#define FE 16
#define H 128
#define NL 2

typedef __attribute__((ext_vector_type(8))) short short8;
typedef __attribute__((ext_vector_type(4))) float float4v;
typedef __hip_bfloat16 bf16;

// ---------------- static workspace ----------------
static constexpr size_t AL = 256;
static constexpr size_t alup(size_t x) { return (x + AL - 1) & ~(AL - 1); }

static constexpr size_t SZ_HF    = (size_t)N_NODES * H * 4;     // 25.6 MB
static constexpr size_t SZ_HB    = (size_t)N_NODES * H * 2;     // 12.8 MB
static constexpr size_t SZ_XB    = (size_t)N_NODES * FN * 2;    // 6.4 MB
static constexpr size_t SZ_PQMB  = (size_t)N_NODES * 384 * 2;   // 38.4 MB
static constexpr size_t SZ_GH    = (size_t)N_NODES * 384 * 4;   // 76.8 MB
static constexpr size_t SZ_GI    = (size_t)N_NODES * 384 * 4;   // 76.8 MB
static constexpr size_t SZ_AGB   = (size_t)N_NODES * H * 2;     // 12.8 MB
static constexpr size_t SZ_NF    = (size_t)N_NODES * 4;
static constexpr size_t SZ_WT    = (size_t)768 * 128 * 2;
static constexpr size_t SZ_WIHT  = (size_t)384 * 128 * 2;
static constexpr size_t SZ_EMBT  = (size_t)128 * 64 * 2;
static constexpr size_t SZ_BBIG  = (size_t)768 * 4;
static constexpr size_t SZ_G128  = (size_t)N_GRAPHS * 128 * 4;
static constexpr size_t SZ_G384  = (size_t)N_GRAPHS * 384 * 4;
static constexpr size_t SZ_GF    = (size_t)N_GRAPHS * 4;
static constexpr size_t SZ_CSE   = (size_t)N_EDGES * 8;

static constexpr size_t OFF_H0    = 0;
static constexpr size_t OFF_H1    = alup(OFF_H0 + SZ_HF);
static constexpr size_t OFF_H0B   = alup(OFF_H1 + SZ_HF);
static constexpr size_t OFF_H1B   = alup(OFF_H0B + SZ_HB);
static constexpr size_t OFF_XB    = alup(OFF_H1B + SZ_HB);
static constexpr size_t OFF_PQMB  = alup(OFF_XB + SZ_XB);
static constexpr size_t OFF_GH    = alup(OFF_PQMB + SZ_PQMB);
static constexpr size_t OFF_GI    = alup(OFF_GH + SZ_GH);
static constexpr size_t OFF_AGB   = alup(OFF_GI + SZ_GI);
static constexpr size_t OFF_ES    = alup(OFF_AGB + SZ_AGB);
static constexpr size_t OFF_WT    = alup(OFF_ES + SZ_NF);
static constexpr size_t OFF_WIHT  = alup(OFF_WT + SZ_WT);
static constexpr size_t OFF_EMBT  = alup(OFF_WIHT + SZ_WIHT);
static constexpr size_t OFF_BBIG  = alup(OFF_EMBT + SZ_EMBT);
static constexpr size_t OFF_G0    = alup(OFF_BBIG + SZ_BBIG);
static constexpr size_t OFF_GA    = alup(OFF_G0 + SZ_G128);
static constexpr size_t OFF_CTX   = alup(OFF_GA + SZ_G128);
static constexpr size_t OFF_GICTX = alup(OFF_CTX + SZ_G128);
static constexpr size_t OFF_GHB   = alup(OFF_GICTX + SZ_G384);
static constexpr size_t OFF_GSUM  = alup(OFF_GHB + SZ_G384);
static constexpr size_t OFF_DEG   = alup(OFF_GSUM + SZ_GF);
static constexpr size_t OFF_OFFS  = alup(OFF_DEG + SZ_NF);
static constexpr size_t OFF_CUR   = alup(OFF_OFFS + SZ_NF + 4);
static constexpr size_t OFF_CSE   = alup(OFF_CUR + SZ_NF);
static constexpr size_t OFF_GHIST = alup(OFF_CSE + SZ_CSE);
static constexpr size_t OFF_GOFFS = alup(OFF_GHIST + SZ_GF);
static constexpr size_t TOTAL_WS  = alup(OFF_GOFFS + SZ_GF + 4);

__device__ unsigned char g_afp_ws[TOTAL_WS];

__device__ inline float bf2f(unsigned short u) {
    unsigned int x = ((unsigned int)u) << 16;
    return __uint_as_float(x);
}

// ---------------- MFMA bf16 GEMM: C = act(A @ Bt^T + bias) ----------------
// A [M,K] bf16 row-major; Bt [Ncol,K] bf16 (i.e. B transposed). K multiple of 32.
// Ncol multiple of 64. mode bit0: relu. bit1: split768 (col<384 -> Cb[r*384+c] bf16,
// col>=384 -> C[r*384+c-384] f32). bit2: dual write (C f32 + Cb bf16, stride Ncol).
__global__ __launch_bounds__(256) void gemm_mfma(
    const bf16* __restrict__ Abf, const bf16* __restrict__ Btbf,
    const float* __restrict__ bias, float* __restrict__ C,
    bf16* __restrict__ Cb, int M, int K, int Ncol, int mode)
{
    const unsigned short* A  = (const unsigned short*)Abf;
    const unsigned short* Bt = (const unsigned short*)Btbf;
    const int l  = threadIdx.x & 63;
    const int w  = threadIdx.x >> 6;
    const int wm = w >> 1, wn = w & 1;
    const int row0 = blockIdx.x * 64 + wm * 32;
    const int col0 = blockIdx.y * 64 + wn * 32;
    const int lr = l & 15;
    const int lk = (l >> 4) * 8;
    float4v acc[2][2] = {};
    for (int k0 = 0; k0 < K; k0 += 32) {
        short8 a[2], b[2];
        #pragma unroll
        for (int i = 0; i < 2; ++i) {
            int r = row0 + i * 16 + lr;
            if (r >= M) r = M - 1;
            a[i] = *(const short8*)(A + (size_t)r * K + k0 + lk);
        }
        #pragma unroll
        for (int j = 0; j < 2; ++j) {
            int c = col0 + j * 16 + lr;
            b[j] = *(const short8*)(Bt + (size_t)c * K + k0 + lk);
        }
        #pragma unroll
        for (int i = 0; i < 2; ++i)
            #pragma unroll
            for (int j = 0; j < 2; ++j)
                acc[i][j] = __builtin_amdgcn_mfma_f32_16x16x32_bf16(a[i], b[j], acc[i][j], 0, 0, 0);
    }
    const int orow = (l >> 4) * 4;
    const int ocol = l & 15;
    #pragma unroll
    for (int i = 0; i < 2; ++i) {
        #pragma unroll
        for (int j = 0; j < 2; ++j) {
            const int gc = col0 + j * 16 + ocol;
            const float bi = bias ? bias[gc] : 0.f;
            #pragma unroll
            for (int r = 0; r < 4; ++r) {
                const int gr = row0 + i * 16 + orow + r;
                if (gr >= M) continue;
                float v = acc[i][j][r] + bi;
                if (mode & 1) v = fmaxf(v, 0.f);
                if (mode & 2) {
                    if (gc < 384) Cb[(size_t)gr * 384 + gc] = __float2bfloat16(v);
                    else          C[(size_t)gr * 384 + (gc - 384)] = v;
                } else {
                    C[(size_t)gr * Ncol + gc] = v;
                    if (mode & 4) Cb[(size_t)gr * Ncol + gc] = __float2bfloat16(v);
                }
            }
        }
    }
}

// ---------------- f32 GEMM (small readout matmuls only) ----------------
#define GBM 64
#define GBN 64
#define GBK 32
__global__ __launch_bounds__(256) void gemm_f32(
    const float* __restrict__ A, const float* __restrict__ B,
    const float* __restrict__ bias, float* __restrict__ C,
    int M, int K, int Ncol)
{
    __shared__ float As[GBK][GBM + 4];
    __shared__ float Bs[GBK][GBN + 4];
    const int tx = threadIdx.x & 15;
    const int ty = threadIdx.x >> 4;
    const int row0 = blockIdx.x * GBM;
    const int col0 = blockIdx.y * GBN;
    float acc[4][4] = {};
    for (int k0 = 0; k0 < K; k0 += GBK) {
        for (int i = threadIdx.x; i < GBM * GBK; i += 256) {
            int r = i / GBK, c = i % GBK;
            float v = 0.f;
            if (row0 + r < M) v = A[(size_t)(row0 + r) * K + k0 + c];
            As[c][r] = v;
        }
        for (int i = threadIdx.x; i < GBK * GBN; i += 256) {
            int r = i / GBN, c = i % GBN;
            float v = 0.f;
            if (col0 + c < Ncol) v = B[(size_t)(k0 + r) * Ncol + col0 + c];
            Bs[r][c] = v;
        }
        __syncthreads();
        #pragma unroll
        for (int k = 0; k < GBK; ++k) {
            float a[4], b[4];
            #pragma unroll
            for (int i = 0; i < 4; ++i) a[i] = As[k][ty * 4 + i];
            #pragma unroll
            for (int j = 0; j < 4; ++j) b[j] = Bs[k][tx * 4 + j];
            #pragma unroll
            for (int i = 0; i < 4; ++i)
                #pragma unroll
                for (int j = 0; j < 4; ++j)
                    acc[i][j] = fmaf(a[i], b[j], acc[i][j]);
        }
        __syncthreads();
    }
    #pragma unroll
    for (int i = 0; i < 4; ++i) {
        int r = row0 + ty * 4 + i;
        if (r >= M) continue;
        #pragma unroll
        for (int j = 0; j < 4; ++j) {
            int c = col0 + tx * 4 + j;
            if (c >= Ncol) continue;
            C[(size_t)r * Ncol + c] = acc[i][j] + (bias ? bias[c] : 0.f);
        }
    }
}

// ---------------- weight packing ----------------
// Wt [768][128] bf16 (transposed big weight), bbig f32 [768]
__global__ void pack_weights_bt(const float* __restrict__ attW1,
                                const float* __restrict__ mlpW,
                                const float* __restrict__ whh,
                                const float* __restrict__ attb1,
                                const float* __restrict__ mlpb,
                                const float* __restrict__ bhh,
                                bf16* __restrict__ wt, float* __restrict__ bbig)
{
    int idx = blockIdx.x * blockDim.x + threadIdx.x;
    if (idx >= 768 * 128) return;
    int j = idx >> 7, k = idx & 127;
    float v;
    if (j < 128)      v = attW1[k * 128 + j];
    else if (j < 256) v = attW1[(128 + k) * 128 + (j - 128)];
    else if (j < 384) v = mlpW[k * 128 + (j - 256)];
    else              v = whh[k * 384 + (j - 384)];
    wt[idx] = __float2bfloat16(v);
    if (k == 0) {
        float b;
        if (j < 128)      b = attb1[j];
        else if (j < 256) b = 0.f;
        else if (j < 384) b = mlpb[j - 256];
        else              b = bhh[j - 384];
        bbig[j] = b;
    }
}

// in [K][Ncol] f32 -> out [Ncol][K] bf16
__global__ void transpose_cast(const float* __restrict__ in, bf16* __restrict__ out,
                               int K, int Ncol)
{
    int idx = blockIdx.x * blockDim.x + threadIdx.x;
    if (idx >= K * Ncol) return;
    int k = idx / Ncol, j = idx % Ncol;
    out[(size_t)j * K + k] = __float2bfloat16(in[idx]);
}

__global__ void cast_bf16_kernel(const float* __restrict__ in, bf16* __restrict__ out, int n)
{
    int idx = blockIdx.x * blockDim.x + threadIdx.x;
    if (idx < n) out[idx] = __float2bfloat16(in[idx]);
}

// ---------------- CSR build ----------------
__global__ void hist_dst_kernel(const int* __restrict__ ei, int* __restrict__ deg) {
    int e = blockIdx.x * blockDim.x + threadIdx.x;
    if (e < N_EDGES) atomicAdd(&deg[ei[N_EDGES + e]], 1);
}
__global__ void hist_batch_kernel(const int* __restrict__ batch, int* __restrict__ hist) {
    int n = blockIdx.x * blockDim.x + threadIdx.x;
    if (n < N_NODES) atomicAdd(&hist[batch[n]], 1);
}
__global__ __launch_bounds__(1024) void scan_excl_kernel(
    const int* __restrict__ in, int* __restrict__ out, int n)
{
    __shared__ int buf[1024];
    __shared__ int carry_s;
    if (threadIdx.x == 0) carry_s = 0;
    __syncthreads();
    for (int base = 0; base < n; base += 1024) {
        int i = base + threadIdx.x;
        int v = (i < n) ? in[i] : 0;
        __syncthreads();
        buf[threadIdx.x] = v;
        __syncthreads();
        for (int off = 1; off < 1024; off <<= 1) {
            int t = 0;
            if (threadIdx.x >= off) t = buf[threadIdx.x - off];
            __syncthreads();
            buf[threadIdx.x] += t;
            __syncthreads();
        }
        int carry = carry_s;
        __syncthreads();
        if (threadIdx.x == 0) carry_s = carry + buf[1023];
        if (i < n) out[i] = carry + buf[threadIdx.x] - v;
    }
    __syncthreads();
    if (threadIdx.x == 0) out[n] = carry_s;
}
// csr_se[pos] = (src, e) for edges sorted by dst
__global__ void scatter_cse_kernel(const int* __restrict__ ei, const int* __restrict__ offs,
                                   int* __restrict__ cur, int2* __restrict__ cse) {
    int e = blockIdx.x * blockDim.x + threadIdx.x;
    if (e >= N_EDGES) return;
    int d = ei[N_EDGES + e];
    int pos = offs[d] + atomicAdd(&cur[d], 1);
    cse[pos] = make_int2(ei[e], e);
}

// ---------------- fused edge attention + aggregation (wave per dst, 4-way ILP) ----------------
__global__ __launch_bounds__(256) void edge_fused_kernel(
    const bf16* __restrict__ pqm_b,
    const int2* __restrict__ cse, const float* __restrict__ ea,
    const float* __restrict__ w1c_g, const float* __restrict__ w2_g,
    const float* __restrict__ b2_g, const float* __restrict__ mlpw2_g,
    const int* __restrict__ offs, bf16* __restrict__ aggrb)
{
    const unsigned short* pqm = (const unsigned short*)pqm_b;
    const int wv = threadIdx.x >> 6, lane = threadIdx.x & 63;
    const int c0 = lane * 2;
    float w1r[16][2], wmr[16][2];
    #pragma unroll
    for (int k = 0; k < 16; ++k) {
        w1r[k][0] = w1c_g[k * 128 + c0];
        w1r[k][1] = w1c_g[k * 128 + c0 + 1];
        wmr[k][0] = mlpw2_g[k * 128 + c0];
        wmr[k][1] = mlpw2_g[k * 128 + c0 + 1];
    }
    const float w20 = w2_g[c0], w21 = w2_g[c0 + 1];
    const float b2 = b2_g[0];
    const int d = blockIdx.x * 4 + wv;
    if (d >= N_NODES) return;
    const ushort2 pu = *(const ushort2*)(pqm + (size_t)d * 384 + c0);
    const float p0 = bf2f(pu.x), p1 = bf2f(pu.y);
    float acc0 = 0.f, acc1 = 0.f, ssum = 0.f;
    const int b = offs[d], en = offs[d + 1];
    int i = b;
    for (; i + 4 <= en; i += 4) {
        int2 se[4];
        #pragma unroll
        for (int t = 0; t < 4; ++t) se[t] = cse[i + t];
        float t0[4], t1[4], m0[4], m1[4];
        #pragma unroll
        for (int t = 0; t < 4; ++t) {
            const unsigned short* ps = pqm + (size_t)se[t].x * 384;
            const ushort2 qu = *(const ushort2*)(ps + 128 + c0);
            const ushort2 mu = *(const ushort2*)(ps + 256 + c0);
            t0[t] = p0 + bf2f(qu.x);
            t1[t] = p1 + bf2f(qu.y);
            m0[t] = bf2f(mu.x);
            m1[t] = bf2f(mu.y);
        }
        #pragma unroll
        for (int c = 0; c < 4; ++c) {
            float4 av[4];
            #pragma unroll
            for (int t = 0; t < 4; ++t)
                av[t] = *(const float4*)(ea + (size_t)se[t].y * 16 + c * 4);
            #pragma unroll
            for (int t = 0; t < 4; ++t) {
                const int k = c * 4;
                t0[t] = fmaf(av[t].x, w1r[k][0], t0[t]);
                t1[t] = fmaf(av[t].x, w1r[k][1], t1[t]);
                m0[t] = fmaf(av[t].x, wmr[k][0], m0[t]);
                m1[t] = fmaf(av[t].x, wmr[k][1], m1[t]);
                t0[t] = fmaf(av[t].y, w1r[k+1][0], t0[t]);
                t1[t] = fmaf(av[t].y, w1r[k+1][1], t1[t]);
                m0[t] = fmaf(av[t].y, wmr[k+1][0], m0[t]);
                m1[t] = fmaf(av[t].y, wmr[k+1][1], m1[t]);
                t0[t] = fmaf(av[t].z, w1r[k+2][0], t0[t]);
                t1[t] = fmaf(av[t].z, w1r[k+2][1], t1[t]);
                m0[t] = fmaf(av[t].z, wmr[k+2][0], m0[t]);
                m1[t] = fmaf(av[t].z, wmr[k+2][1], m1[t]);
                t0[t] = fmaf(av[t].w, w1r[k+3][0], t0[t]);
                t1[t] = fmaf(av[t].w, w1r[k+3][1], t1[t]);
                m0[t] = fmaf(av[t].w, wmr[k+3][0], m0[t]);
                m1[t] = fmaf(av[t].w, wmr[k+3][1], m1[t]);
            }
        }
        float sp[4];
        #pragma unroll
        for (int t = 0; t < 4; ++t) {
            float a0 = (t0[t] > 0.f) ? t0[t] : 0.2f * t0[t];
            float a1 = (t1[t] > 0.f) ? t1[t] : 0.2f * t1[t];
            sp[t] = a0 * w20 + a1 * w21;
        }
        #pragma unroll
        for (int off = 32; off; off >>= 1) {
            #pragma unroll
            for (int t = 0; t < 4; ++t) sp[t] += __shfl_xor(sp[t], off);
        }
        #pragma unroll
        for (int t = 0; t < 4; ++t) {
            const float ex = expf(sp[t] + b2);
            ssum += ex;
            acc0 = fmaf(ex, fmaxf(m0[t], 0.f), acc0);
            acc1 = fmaf(ex, fmaxf(m1[t], 0.f), acc1);
        }
    }
    for (; i < en; ++i) {
        const int2 se = cse[i];
        const unsigned short* ps = pqm + (size_t)se.x * 384;
        const ushort2 qu = *(const ushort2*)(ps + 128 + c0);
        const ushort2 mu = *(const ushort2*)(ps + 256 + c0);
        float t0 = p0 + bf2f(qu.x), t1 = p1 + bf2f(qu.y);
        float m0 = bf2f(mu.x), m1 = bf2f(mu.y);
        const float4* eap = (const float4*)(ea + (size_t)se.y * 16);
        #pragma unroll
        for (int c = 0; c < 4; ++c) {
            float4 av = eap[c];
            const int k = c * 4;
            t0 = fmaf(av.x, w1r[k][0], t0);   t1 = fmaf(av.x, w1r[k][1], t1);
            m0 = fmaf(av.x, wmr[k][0], m0);   m1 = fmaf(av.x, wmr[k][1], m1);
            t0 = fmaf(av.y, w1r[k+1][0], t0); t1 = fmaf(av.y, w1r[k+1][1], t1);
            m0 = fmaf(av.y, wmr[k+1][0], m0); m1 = fmaf(av.y, wmr[k+1][1], m1);
            t0 = fmaf(av.z, w1r[k+2][0], t0); t1 = fmaf(av.z, w1r[k+2][1], t1);
            m0 = fmaf(av.z, wmr[k+2][0], m0); m1 = fmaf(av.z, wmr[k+2][1], m1);
            t0 = fmaf(av.w, w1r[k+3][0], t0); t1 = fmaf(av.w, w1r[k+3][1], t1);
            m0 = fmaf(av.w, wmr[k+3][0], m0); m1 = fmaf(av.w, wmr[k+3][1], m1);
        }
        float a0 = (t0 > 0.f) ? t0 : 0.2f * t0;
        float a1 = (t1 > 0.f) ? t1 : 0.2f * t1;
        float sp = a0 * w20 + a1 * w21;
        #pragma unroll
        for (int off = 32; off; off >>= 1) sp += __shfl_xor(sp, off);
        const float ex = expf(sp + b2);
        ssum += ex;
        acc0 = fmaf(ex, fmaxf(m0, 0.f), acc0);
        acc1 = fmaf(ex, fmaxf(m1, 0.f), acc1);
    }
    const float inv = 1.f / (ssum + 1e-16f);
    bf16* outp = aggrb + (size_t)d * 128 + c0;
    outp[0] = __float2bfloat16(acc0 * inv);
    outp[1] = __float2bfloat16(acc1 * inv);
}

// ---------------- GRU elementwise ----------------
__global__ void gru_elem_kernel(const float* __restrict__ gi,
                                const float* __restrict__ gh,
                                const float* __restrict__ hold, float* __restrict__ hnew,
                                bf16* __restrict__ hnewb, int rows)
{
    int idx = blockIdx.x * blockDim.x + threadIdx.x;
    if (idx >= rows * H) return;
    int r = idx >> 7, c = idx & 127;
    float ir = gi[(size_t)r * 384 + c];
    float iz = gi[(size_t)r * 384 + 128 + c];
    float in = gi[(size_t)r * 384 + 256 + c];
    float hr = gh[(size_t)r * 384 + c];
    float hz = gh[(size_t)r * 384 + 128 + c];
    float hn = gh[(size_t)r * 384 + 256 + c];
    float rg = 1.f / (1.f + expf(-(ir + hr)));
    float zg = 1.f / (1.f + expf(-(iz + hz)));
    float ng = tanhf(in + rg * hn);
    float hv = hold[idx];
    float o = (1.f - zg) * ng + zg * hv;
    hnew[idx] = o;
    if (hnewb) hnewb[idx] = __float2bfloat16(o);
}

// ---------------- graph pooling / readout ----------------
__global__ __launch_bounds__(128) void graph_pool_sum(
    const float* __restrict__ h, const int* __restrict__ goffs, float* __restrict__ g0)
{
    int g = blockIdx.x, c = threadIdx.x;
    int b = goffs[g], e2 = goffs[g + 1];
    float acc = 0.f;
    for (int i = b; i < e2; ++i) acc += h[(size_t)i * 128 + c];
    g0[(size_t)g * 128 + c] = acc;
}

__global__ __launch_bounds__(128) void node_score_kernel(
    const float* __restrict__ h, const float* __restrict__ W1,
    const float* __restrict__ b1, const float* __restrict__ W2,
    const float* __restrict__ b2, const int* __restrict__ batch,
    float* __restrict__ es, float* __restrict__ gsum)
{
    __shared__ float hrow[8][128];
    __shared__ float red[8][128];
    int base = blockIdx.x * 8;
    int c = threadIdx.x;
    #pragma unroll
    for (int r = 0; r < 8; ++r) {
        int nid = base + r;
        hrow[r][c] = (nid < N_NODES) ? h[(size_t)nid * 128 + c] : 0.f;
    }
    __syncthreads();
    float acc[8];
    float bb = b1[c];
    #pragma unroll
    for (int r = 0; r < 8; ++r) acc[r] = bb;
    for (int k = 0; k < 128; ++k) {
        float w = W1[k * 128 + c];
        #pragma unroll
        for (int r = 0; r < 8; ++r) acc[r] = fmaf(hrow[r][k], w, acc[r]);
    }
    float w2 = W2[c];
    #pragma unroll
    for (int r = 0; r < 8; ++r) red[r][c] = tanhf(acc[r]) * w2;
    __syncthreads();
    for (int off = 64; off; off >>= 1) {
        if (c < off) {
            #pragma unroll
            for (int r = 0; r < 8; ++r) red[r][c] += red[r][c + off];
        }
        __syncthreads();
    }
    if (c < 8) {
        int nid = base + c;
        if (nid < N_NODES) {
            float s = red[c][0] + b2[0];
            float ex = expf(s);
            es[nid] = ex;
            atomicAdd(&gsum[batch[nid]], ex);
        }
    }
}

__global__ __launch_bounds__(128) void graph_ctx_kernel(
    const float* __restrict__ h, const int* __restrict__ goffs,
    const float* __restrict__ es, const float* __restrict__ gsum,
    float* __restrict__ ctx)
{
    int g = blockIdx.x, c = threadIdx.x;
    float invs = 1.f / (gsum[g] + 1e-16f);
    int b = goffs[g], e2 = goffs[g + 1];
    float acc = 0.f;
    for (int i = b; i < e2; ++i) acc = fmaf(es[i] * invs, h[(size_t)i * 128 + c], acc);
    ctx[(size_t)g * 128 + c] = acc;
}

extern "C" void kernel_launch(void* const* d_in, const int* in_sizes, int n_in,
                              void* d_out, int out_size, void* d_ws, size_t ws_size,
                              hipStream_t stream) {
    const float* x      = (const float*)d_in[0];
    const int*   ei     = (const int*)d_in[1];
    const float* ea     = (const float*)d_in[2];
    const int*   batch  = (const int*)d_in[3];
    const float* embW   = (const float*)d_in[4];
    const float* embB   = (const float*)d_in[5];
    const float* attW1  = (const float*)d_in[6];
    const float* attb1  = (const float*)d_in[7];
    const float* attW2  = (const float*)d_in[8];
    const float* attb2  = (const float*)d_in[9];
    const float* mlpW   = (const float*)d_in[10];
    const float* mlpb   = (const float*)d_in[11];
    const float* gWih   = (const float*)d_in[12];
    const float* gWhh   = (const float*)d_in[13];
    const float* gbih   = (const float*)d_in[14];
    const float* gbhh   = (const float*)d_in[15];
    const float* gattW1 = (const float*)d_in[16];
    const float* gattb1 = (const float*)d_in[17];
    const float* gattW2 = (const float*)d_in[18];
    const float* gattb2 = (const float*)d_in[19];
    const float* ggWih  = (const float*)d_in[20];
    const float* ggWhh  = (const float*)d_in[21];
    const float* ggbih  = (const float*)d_in[22];
    const float* ggbhh  = (const float*)d_in[23];
    float* out = (float*)d_out;

    void* basep = nullptr;
    (void)hipGetSymbolAddress(&basep, HIP_SYMBOL(g_afp_ws));
    char* base = (char*)basep;
    float* h0    = (float*)(base + OFF_H0);
    float* h1    = (float*)(base + OFF_H1);
    bf16*  h0b   = (bf16*)(base + OFF_H0B);
    bf16*  h1b   = (bf16*)(base + OFF_H1B);
    bf16*  xb    = (bf16*)(base + OFF_XB);
    bf16*  pqmb  = (bf16*)(base + OFF_PQMB);
    float* gh    = (float*)(base + OFF_GH);
    float* gi    = (float*)(base + OFF_GI);
    bf16*  aggrb = (bf16*)(base + OFF_AGB);
    float* es    = (float*)(base + OFF_ES);
    bf16*  wt    = (bf16*)(base + OFF_WT);
    bf16*  wiht  = (bf16*)(base + OFF_WIHT);
    bf16*  embt  = (bf16*)(base + OFF_EMBT);
    float* bbig  = (float*)(base + OFF_BBIG);
    float* g0b   = (float*)(base + OFF_G0);
    float* gAb   = (float*)(base + OFF_GA);
    float* ctx   = (float*)(base + OFF_CTX);
    float* gictx = (float*)(base + OFF_GICTX);
    float* ghb   = (float*)(base + OFF_GHB);
    float* gsum  = (float*)(base + OFF_GSUM);
    int*   deg   = (int*)(base + OFF_DEG);
    int*   offs  = (int*)(base + OFF_OFFS);
    int*   cur   = (int*)(base + OFF_CUR);
    int2*  cse   = (int2*)(base + OFF_CSE);
    int*   ghist = (int*)(base + OFF_GHIST);
    int*   goffs = (int*)(base + OFF_GOFFS);

    (void)hipMemsetAsync(deg, 0, SZ_NF, stream);
    (void)hipMemsetAsync(cur, 0, SZ_NF, stream);
    (void)hipMemsetAsync(ghist, 0, SZ_GF, stream);
    (void)hipMemsetAsync(gsum, 0, SZ_GF, stream);

    hist_dst_kernel<<<(N_EDGES + 255) / 256, 256, 0, stream>>>(ei, deg);
    scan_excl_kernel<<<1, 1024, 0, stream>>>(deg, offs, N_NODES);
    scatter_cse_kernel<<<(N_EDGES + 255) / 256, 256, 0, stream>>>(ei, offs, cur, cse);
    hist_batch_kernel<<<(N_NODES + 255) / 256, 256, 0, stream>>>(batch, ghist);
    scan_excl_kernel<<<1, 1024, 0, stream>>>(ghist, goffs, N_GRAPHS);

    // input casts / weight transposes
    cast_bf16_kernel<<<(N_NODES * FN + 255) / 256, 256, 0, stream>>>(x, xb, N_NODES * FN);
    transpose_cast<<<(FN * 128 + 255) / 256, 256, 0, stream>>>(embW, embt, FN, 128);

    // embedding: h0 = relu(xb @ embW + embB), dual write f32 + bf16
    {
        dim3 g((N_NODES + 63) / 64, 128 / 64);
        gemm_mfma<<<g, 256, 0, stream>>>(xb, embt, embB, h0, h0b, N_NODES, FN, 128, 1 | 4);
    }

    float* hcur = h0;  bf16* hcurb = h0b;
    float* hnext = h1; bf16* hnextb = h1b;
    for (int l = 0; l < NL; ++l) {
        pack_weights_bt<<<(768 * 128 + 255) / 256, 256, 0, stream>>>(
            attW1 + (size_t)l * 272 * 128, mlpW + (size_t)l * 144 * 128,
            gWhh + (size_t)l * 128 * 384, attb1 + l * 128, mlpb + l * 128,
            gbhh + l * 384, wt, bbig);
        {
            dim3 g((N_NODES + 63) / 64, 768 / 64);
            gemm_mfma<<<g, 256, 0, stream>>>(hcurb, wt, bbig, gh, pqmb,
                                             N_NODES, 128, 768, 2);
        }
        edge_fused_kernel<<<(N_NODES + 3) / 4, 256, 0, stream>>>(
            pqmb, cse, ea, attW1 + (size_t)l * 272 * 128 + 256 * 128,
            attW2 + (size_t)l * 128, attb2 + l,
            mlpW + (size_t)l * 144 * 128 + 128 * 128,
            offs, aggrb);
        transpose_cast<<<(128 * 384 + 255) / 256, 256, 0, stream>>>(
            gWih + (size_t)l * 128 * 384, wiht, 128, 384);
        {
            dim3 g((N_NODES + 63) / 64, 384 / 64);
            gemm_mfma<<<g, 256, 0, stream>>>(aggrb, wiht, gbih + l * 384, gi, nullptr,
                                             N_NODES, 128, 384, 0);
        }
        gru_elem_kernel<<<((size_t)N_NODES * H + 255) / 256, 256, 0, stream>>>(
            gi, gh, hcur, hnext, hnextb, N_NODES);
        float* t = hcur; hcur = hnext; hnext = t;
        bf16* tb = hcurb; hcurb = hnextb; hnextb = tb;
    }

    // readout (h fixed across T -> ctx computed once)
    graph_pool_sum<<<N_GRAPHS, 128, 0, stream>>>(hcur, goffs, g0b);
    node_score_kernel<<<(N_NODES + 7) / 8, 128, 0, stream>>>(
        hcur, gattW1, gattb1, gattW2, gattb2, batch, es, gsum);
    graph_ctx_kernel<<<N_GRAPHS, 128, 0, stream>>>(hcur, goffs, es, gsum, ctx);

    dim3 gg((N_GRAPHS + 63) / 64, 384 / 64);
    gemm_f32<<<gg, 256, 0, stream>>>(ctx, ggWih, ggbih, gictx, N_GRAPHS, H, 384);
    gemm_f32<<<gg, 256, 0, stream>>>(g0b, ggWhh, ggbhh, ghb, N_GRAPHS, H, 384);
    gru_elem_kernel<<<((size_t)N_GRAPHS * H + 255) / 256, 256, 0, stream>>>(
        gictx, ghb, g0b, gAb, nullptr, N_GRAPHS);
    gemm_f32<<<gg, 256, 0, stream>>>(gAb, ggWhh, ggbhh, ghb, N_GRAPHS, H, 384);
    gru_elem_kernel<<<((size_t)N_GRAPHS * H + 255) / 256, 256, 0, stream>>>(
        gictx, ghb, gAb, out, nullptr, N_GRAPHS);
}

// Round 6
// 1051.011 us; speedup vs baseline: 1.7074x; 1.4784x over previous
//
#include <hip/hip_runtime.h>
#include <hip/hip_bf16.h>
#include <math.h>

#define N_NODES 50000
#define N_EDGES 640000
#define N_GRAPHS 2000
#define FN 64
#define FE 16
#define H 128
#define NL 2
#define DPW 4   // dsts per wave in edge kernel

typedef __attribute__((ext_vector_type(8))) short short8;
typedef __attribute__((ext_vector_type(4))) float float4v;
typedef __hip_bfloat16 bf16;

// ---------------- static workspace ----------------
static constexpr size_t AL = 256;
static constexpr size_t alup(size_t x) { return (x + AL - 1) & ~(AL - 1); }

static constexpr size_t SZ_HF    = (size_t)N_NODES * H * 4;
static constexpr size_t SZ_HB    = (size_t)N_NODES * H * 2;
static constexpr size_t SZ_XB    = (size_t)N_NODES * FN * 2;
static constexpr size_t SZ_PQMB  = (size_t)N_NODES * 384 * 2;
static constexpr size_t SZ_GH    = (size_t)N_NODES * 384 * 4;
static constexpr size_t SZ_GI    = (size_t)N_NODES * 384 * 4;
static constexpr size_t SZ_AGB   = (size_t)N_NODES * H * 2;
static constexpr size_t SZ_NF    = (size_t)N_NODES * 4;
static constexpr size_t SZ_WT    = (size_t)768 * 128 * 2;
static constexpr size_t SZ_WIHT  = (size_t)384 * 128 * 2;
static constexpr size_t SZ_EMBT  = (size_t)128 * 64 * 2;
static constexpr size_t SZ_BBIG  = (size_t)768 * 4;
static constexpr size_t SZ_G128  = (size_t)N_GRAPHS * 128 * 4;
static constexpr size_t SZ_G384  = (size_t)N_GRAPHS * 384 * 4;
static constexpr size_t SZ_GF    = (size_t)N_GRAPHS * 4;
static constexpr size_t SZ_CSE   = (size_t)N_EDGES * 8;

static constexpr size_t OFF_H0    = 0;
static constexpr size_t OFF_H1    = alup(OFF_H0 + SZ_HF);
static constexpr size_t OFF_H0B   = alup(OFF_H1 + SZ_HF);
static constexpr size_t OFF_H1B   = alup(OFF_H0B + SZ_HB);
static constexpr size_t OFF_XB    = alup(OFF_H1B + SZ_HB);
static constexpr size_t OFF_PQMB  = alup(OFF_XB + SZ_XB);
static constexpr size_t OFF_GH    = alup(OFF_PQMB + SZ_PQMB);
static constexpr size_t OFF_GI    = alup(OFF_GH + SZ_GH);
static constexpr size_t OFF_AGB   = alup(OFF_GI + SZ_GI);
static constexpr size_t OFF_ES    = alup(OFF_AGB + SZ_AGB);
static constexpr size_t OFF_WT    = alup(OFF_ES + SZ_NF);
static constexpr size_t OFF_WIHT  = alup(OFF_WT + SZ_WT);
static constexpr size_t OFF_EMBT  = alup(OFF_WIHT + SZ_WIHT);
static constexpr size_t OFF_BBIG  = alup(OFF_EMBT + SZ_EMBT);
static constexpr size_t OFF_G0    = alup(OFF_BBIG + SZ_BBIG);
static constexpr size_t OFF_GA    = alup(OFF_G0 + SZ_G128);
static constexpr size_t OFF_CTX   = alup(OFF_GA + SZ_G128);
static constexpr size_t OFF_GICTX = alup(OFF_CTX + SZ_G128);
static constexpr size_t OFF_GHB   = alup(OFF_GICTX + SZ_G384);
static constexpr size_t OFF_GSUM  = alup(OFF_GHB + SZ_G384);
static constexpr size_t OFF_DEG   = alup(OFF_GSUM + SZ_GF);
static constexpr size_t OFF_OFFS  = alup(OFF_DEG + SZ_NF);
static constexpr size_t OFF_CUR   = alup(OFF_OFFS + SZ_NF + 4);
static constexpr size_t OFF_CSE   = alup(OFF_CUR + SZ_NF);
static constexpr size_t OFF_GHIST = alup(OFF_CSE + SZ_CSE);
static constexpr size_t OFF_GOFFS = alup(OFF_GHIST + SZ_GF);
static constexpr size_t TOTAL_WS  = alup(OFF_GOFFS + SZ_GF + 4);

__device__ unsigned char g_afp_ws[TOTAL_WS];

__device__ inline float bf2f(unsigned short u) {
    unsigned int x = ((unsigned int)u) << 16;
    return __uint_as_float(x);
}

// ---------------- MFMA bf16 GEMM ----------------
__global__ __launch_bounds__(256) void gemm_mfma(
    const bf16* __restrict__ Abf, const bf16* __restrict__ Btbf,
    const float* __restrict__ bias, float* __restrict__ C,
    bf16* __restrict__ Cb, int M, int K, int Ncol, int mode)
{
    const unsigned short* A  = (const unsigned short*)Abf;
    const unsigned short* Bt = (const unsigned short*)Btbf;
    const int l  = threadIdx.x & 63;
    const int w  = threadIdx.x >> 6;
    const int wm = w >> 1, wn = w & 1;
    const int row0 = blockIdx.x * 64 + wm * 32;
    const int col0 = blockIdx.y * 64 + wn * 32;
    const int lr = l & 15;
    const int lk = (l >> 4) * 8;
    float4v acc[2][2] = {};
    for (int k0 = 0; k0 < K; k0 += 32) {
        short8 a[2], b[2];
        #pragma unroll
        for (int i = 0; i < 2; ++i) {
            int r = row0 + i * 16 + lr;
            if (r >= M) r = M - 1;
            a[i] = *(const short8*)(A + (size_t)r * K + k0 + lk);
        }
        #pragma unroll
        for (int j = 0; j < 2; ++j) {
            int c = col0 + j * 16 + lr;
            b[j] = *(const short8*)(Bt + (size_t)c * K + k0 + lk);
        }
        #pragma unroll
        for (int i = 0; i < 2; ++i)
            #pragma unroll
            for (int j = 0; j < 2; ++j)
                acc[i][j] = __builtin_amdgcn_mfma_f32_16x16x32_bf16(a[i], b[j], acc[i][j], 0, 0, 0);
    }
    const int orow = (l >> 4) * 4;
    const int ocol = l & 15;
    #pragma unroll
    for (int i = 0; i < 2; ++i) {
        #pragma unroll
        for (int j = 0; j < 2; ++j) {
            const int gc = col0 + j * 16 + ocol;
            const float bi = bias ? bias[gc] : 0.f;
            #pragma unroll
            for (int r = 0; r < 4; ++r) {
                const int gr = row0 + i * 16 + orow + r;
                if (gr >= M) continue;
                float v = acc[i][j][r] + bi;
                if (mode & 1) v = fmaxf(v, 0.f);
                if (mode & 2) {
                    if (gc < 384) Cb[(size_t)gr * 384 + gc] = __float2bfloat16(v);
                    else          C[(size_t)gr * 384 + (gc - 384)] = v;
                } else {
                    C[(size_t)gr * Ncol + gc] = v;
                    if (mode & 4) Cb[(size_t)gr * Ncol + gc] = __float2bfloat16(v);
                }
            }
        }
    }
}

// ---------------- f32 GEMM (small readout matmuls only) ----------------
#define GBM 64
#define GBN 64
#define GBK 32
__global__ __launch_bounds__(256) void gemm_f32(
    const float* __restrict__ A, const float* __restrict__ B,
    const float* __restrict__ bias, float* __restrict__ C,
    int M, int K, int Ncol)
{
    __shared__ float As[GBK][GBM + 4];
    __shared__ float Bs[GBK][GBN + 4];
    const int tx = threadIdx.x & 15;
    const int ty = threadIdx.x >> 4;
    const int row0 = blockIdx.x * GBM;
    const int col0 = blockIdx.y * GBN;
    float acc[4][4] = {};
    for (int k0 = 0; k0 < K; k0 += GBK) {
        for (int i = threadIdx.x; i < GBM * GBK; i += 256) {
            int r = i / GBK, c = i % GBK;
            float v = 0.f;
            if (row0 + r < M) v = A[(size_t)(row0 + r) * K + k0 + c];
            As[c][r] = v;
        }
        for (int i = threadIdx.x; i < GBK * GBN; i += 256) {
            int r = i / GBN, c = i % GBN;
            float v = 0.f;
            if (col0 + c < Ncol) v = B[(size_t)(k0 + r) * Ncol + col0 + c];
            Bs[r][c] = v;
        }
        __syncthreads();
        #pragma unroll
        for (int k = 0; k < GBK; ++k) {
            float a[4], b[4];
            #pragma unroll
            for (int i = 0; i < 4; ++i) a[i] = As[k][ty * 4 + i];
            #pragma unroll
            for (int j = 0; j < 4; ++j) b[j] = Bs[k][tx * 4 + j];
            #pragma unroll
            for (int i = 0; i < 4; ++i)
                #pragma unroll
                for (int j = 0; j < 4; ++j)
                    acc[i][j] = fmaf(a[i], b[j], acc[i][j]);
        }
        __syncthreads();
    }
    #pragma unroll
    for (int i = 0; i < 4; ++i) {
        int r = row0 + ty * 4 + i;
        if (r >= M) continue;
        #pragma unroll
        for (int j = 0; j < 4; ++j) {
            int c = col0 + tx * 4 + j;
            if (c >= Ncol) continue;
            C[(size_t)r * Ncol + c] = acc[i][j] + (bias ? bias[c] : 0.f);
        }
    }
}

// ---------------- weight packing ----------------
__global__ void pack_weights_bt(const float* __restrict__ attW1,
                                const float* __restrict__ mlpW,
                                const float* __restrict__ whh,
                                const float* __restrict__ attb1,
                                const float* __restrict__ mlpb,
                                const float* __restrict__ bhh,
                                bf16* __restrict__ wt, float* __restrict__ bbig)
{
    int idx = blockIdx.x * blockDim.x + threadIdx.x;
    if (idx >= 768 * 128) return;
    int j = idx >> 7, k = idx & 127;
    float v;
    if (j < 128)      v = attW1[k * 128 + j];
    else if (j < 256) v = attW1[(128 + k) * 128 + (j - 128)];
    else if (j < 384) v = mlpW[k * 128 + (j - 256)];
    else              v = whh[k * 384 + (j - 384)];
    wt[idx] = __float2bfloat16(v);
    if (k == 0) {
        float b;
        if (j < 128)      b = attb1[j];
        else if (j < 256) b = 0.f;
        else if (j < 384) b = mlpb[j - 256];
        else              b = bhh[j - 384];
        bbig[j] = b;
    }
}

__global__ void transpose_cast(const float* __restrict__ in, bf16* __restrict__ out,
                               int K, int Ncol)
{
    int idx = blockIdx.x * blockDim.x + threadIdx.x;
    if (idx >= K * Ncol) return;
    int k = idx / Ncol, j = idx % Ncol;
    out[(size_t)j * K + k] = __float2bfloat16(in[idx]);
}

__global__ void cast_bf16_kernel(const float* __restrict__ in, bf16* __restrict__ out, int n)
{
    int idx = blockIdx.x * blockDim.x + threadIdx.x;
    if (idx < n) out[idx] = __float2bfloat16(in[idx]);
}

// ---------------- CSR build ----------------
__global__ void hist_dst_kernel(const int* __restrict__ ei, int* __restrict__ deg) {
    int e = blockIdx.x * blockDim.x + threadIdx.x;
    if (e < N_EDGES) atomicAdd(&deg[ei[N_EDGES + e]], 1);
}
__global__ void hist_batch_kernel(const int* __restrict__ batch, int* __restrict__ hist) {
    int n = blockIdx.x * blockDim.x + threadIdx.x;
    if (n < N_NODES) atomicAdd(&hist[batch[n]], 1);
}
__global__ __launch_bounds__(1024) void scan_excl_kernel(
    const int* __restrict__ in, int* __restrict__ out, int n)
{
    __shared__ int buf[1024];
    __shared__ int carry_s;
    if (threadIdx.x == 0) carry_s = 0;
    __syncthreads();
    for (int base = 0; base < n; base += 1024) {
        int i = base + threadIdx.x;
        int v = (i < n) ? in[i] : 0;
        __syncthreads();
        buf[threadIdx.x] = v;
        __syncthreads();
        for (int off = 1; off < 1024; off <<= 1) {
            int t = 0;
            if (threadIdx.x >= off) t = buf[threadIdx.x - off];
            __syncthreads();
            buf[threadIdx.x] += t;
            __syncthreads();
        }
        int carry = carry_s;
        __syncthreads();
        if (threadIdx.x == 0) carry_s = carry + buf[1023];
        if (i < n) out[i] = carry + buf[threadIdx.x] - v;
    }
    __syncthreads();
    if (threadIdx.x == 0) out[n] = carry_s;
}
__global__ void scatter_cse_kernel(const int* __restrict__ ei, const int* __restrict__ offs,
                                   int* __restrict__ cur, int2* __restrict__ cse) {
    int e = blockIdx.x * blockDim.x + threadIdx.x;
    if (e >= N_EDGES) return;
    int d = ei[N_EDGES + e];
    int pos = offs[d] + atomicAdd(&cur[d], 1);
    cse[pos] = make_int2(ei[e], e);
}

// ---------------- fused edge attention + aggregation ----------------
// wave per dst-group (DPW consecutive dsts); 2-deep software pipeline per edge.
__global__ __launch_bounds__(256) void edge_fused_kernel(
    const bf16* __restrict__ pqm_b,
    const int2* __restrict__ cse, const float* __restrict__ ea,
    const float* __restrict__ w1c_g, const float* __restrict__ w2_g,
    const float* __restrict__ b2_g, const float* __restrict__ mlpw2_g,
    const int* __restrict__ offs, bf16* __restrict__ aggrb)
{
    const unsigned short* pqm = (const unsigned short*)pqm_b;
    const int wv = threadIdx.x >> 6, lane = threadIdx.x & 63;
    const int c0 = lane * 2;
    float w1r[16][2], wmr[16][2];
    #pragma unroll
    for (int k = 0; k < 16; ++k) {
        w1r[k][0] = w1c_g[k * 128 + c0];
        w1r[k][1] = w1c_g[k * 128 + c0 + 1];
        wmr[k][0] = mlpw2_g[k * 128 + c0];
        wmr[k][1] = mlpw2_g[k * 128 + c0 + 1];
    }
    const float w20 = w2_g[c0], w21 = w2_g[c0 + 1];
    const float b2 = b2_g[0];
    const int dbase = __builtin_amdgcn_readfirstlane((blockIdx.x * 4 + wv) * DPW);

    for (int rep = 0; rep < DPW; ++rep) {
        const int d = dbase + rep;
        if (d >= N_NODES) break;
        const ushort2 pu = *(const ushort2*)(pqm + (size_t)d * 384 + c0);
        const float p0 = bf2f(pu.x), p1 = bf2f(pu.y);
        float acc0 = 0.f, acc1 = 0.f, ssum = 0.f;
        const int b = offs[d], en = offs[d + 1];
        if (b < en) {
            // prefetch edge b
            int2 se = cse[b];
            const unsigned short* ps = pqm + (size_t)se.x * 384;
            ushort2 qu = *(const ushort2*)(ps + 128 + c0);
            ushort2 mu = *(const ushort2*)(ps + 256 + c0);
            const float4* eap = (const float4*)(ea + (size_t)se.y * 16);
            float4 e0 = eap[0], e1 = eap[1], e2 = eap[2], e3 = eap[3];
            for (int i = b; i < en; ++i) {
                // capture current into compute regs
                float t0 = p0 + bf2f(qu.x), t1 = p1 + bf2f(qu.y);
                float m0 = bf2f(mu.x), m1 = bf2f(mu.y);
                float er[16];
                er[0]=e0.x; er[1]=e0.y; er[2]=e0.z; er[3]=e0.w;
                er[4]=e1.x; er[5]=e1.y; er[6]=e1.z; er[7]=e1.w;
                er[8]=e2.x; er[9]=e2.y; er[10]=e2.z; er[11]=e2.w;
                er[12]=e3.x; er[13]=e3.y; er[14]=e3.z; er[15]=e3.w;
                // issue next edge's loads (land during compute below)
                if (i + 1 < en) {
                    se = cse[i + 1];
                    const unsigned short* psn = pqm + (size_t)se.x * 384;
                    qu = *(const ushort2*)(psn + 128 + c0);
                    mu = *(const ushort2*)(psn + 256 + c0);
                    const float4* eapn = (const float4*)(ea + (size_t)se.y * 16);
                    e0 = eapn[0]; e1 = eapn[1]; e2 = eapn[2]; e3 = eapn[3];
                }
                // compute current edge
                #pragma unroll
                for (int k = 0; k < 16; ++k) {
                    t0 = fmaf(er[k], w1r[k][0], t0);
                    t1 = fmaf(er[k], w1r[k][1], t1);
                    m0 = fmaf(er[k], wmr[k][0], m0);
                    m1 = fmaf(er[k], wmr[k][1], m1);
                }
                float a0 = (t0 > 0.f) ? t0 : 0.2f * t0;
                float a1 = (t1 > 0.f) ? t1 : 0.2f * t1;
                float sp = a0 * w20 + a1 * w21;
                #pragma unroll
                for (int off = 32; off; off >>= 1) sp += __shfl_xor(sp, off);
                const float ex = __expf(sp + b2);
                ssum += ex;
                acc0 = fmaf(ex, fmaxf(m0, 0.f), acc0);
                acc1 = fmaf(ex, fmaxf(m1, 0.f), acc1);
            }
        }
        const float inv = 1.f / (ssum + 1e-16f);
        bf16* outp = aggrb + (size_t)d * 128 + c0;
        outp[0] = __float2bfloat16(acc0 * inv);
        outp[1] = __float2bfloat16(acc1 * inv);
    }
}

// ---------------- GRU elementwise ----------------
__global__ void gru_elem_kernel(const float* __restrict__ gi,
                                const float* __restrict__ gh,
                                const float* __restrict__ hold, float* __restrict__ hnew,
                                bf16* __restrict__ hnewb, int rows)
{
    int idx = blockIdx.x * blockDim.x + threadIdx.x;
    if (idx >= rows * H) return;
    int r = idx >> 7, c = idx & 127;
    float ir = gi[(size_t)r * 384 + c];
    float iz = gi[(size_t)r * 384 + 128 + c];
    float in = gi[(size_t)r * 384 + 256 + c];
    float hr = gh[(size_t)r * 384 + c];
    float hz = gh[(size_t)r * 384 + 128 + c];
    float hn = gh[(size_t)r * 384 + 256 + c];
    float rg = 1.f / (1.f + __expf(-(ir + hr)));
    float zg = 1.f / (1.f + __expf(-(iz + hz)));
    float ng = tanhf(in + rg * hn);
    float hv = hold[idx];
    float o = (1.f - zg) * ng + zg * hv;
    hnew[idx] = o;
    if (hnewb) hnewb[idx] = __float2bfloat16(o);
}

// ---------------- graph pooling / readout ----------------
__global__ __launch_bounds__(128) void graph_pool_sum(
    const float* __restrict__ h, const int* __restrict__ goffs, float* __restrict__ g0)
{
    int g = blockIdx.x, c = threadIdx.x;
    int b = goffs[g], e2 = goffs[g + 1];
    float acc = 0.f;
    for (int i = b; i < e2; ++i) acc += h[(size_t)i * 128 + c];
    g0[(size_t)g * 128 + c] = acc;
}

__global__ __launch_bounds__(128) void node_score_kernel(
    const float* __restrict__ h, const float* __restrict__ W1,
    const float* __restrict__ b1, const float* __restrict__ W2,
    const float* __restrict__ b2, const int* __restrict__ batch,
    float* __restrict__ es, float* __restrict__ gsum)
{
    __shared__ float hrow[8][128];
    __shared__ float red[8][128];
    int base = blockIdx.x * 8;
    int c = threadIdx.x;
    #pragma unroll
    for (int r = 0; r < 8; ++r) {
        int nid = base + r;
        hrow[r][c] = (nid < N_NODES) ? h[(size_t)nid * 128 + c] : 0.f;
    }
    __syncthreads();
    float acc[8];
    float bb = b1[c];
    #pragma unroll
    for (int r = 0; r < 8; ++r) acc[r] = bb;
    for (int k = 0; k < 128; ++k) {
        float w = W1[k * 128 + c];
        #pragma unroll
        for (int r = 0; r < 8; ++r) acc[r] = fmaf(hrow[r][k], w, acc[r]);
    }
    float w2 = W2[c];
    #pragma unroll
    for (int r = 0; r < 8; ++r) red[r][c] = tanhf(acc[r]) * w2;
    __syncthreads();
    for (int off = 64; off; off >>= 1) {
        if (c < off) {
            #pragma unroll
            for (int r = 0; r < 8; ++r) red[r][c] += red[r][c + off];
        }
        __syncthreads();
    }
    if (c < 8) {
        int nid = base + c;
        if (nid < N_NODES) {
            float s = red[c][0] + b2[0];
            float ex = __expf(s);
            es[nid] = ex;
            atomicAdd(&gsum[batch[nid]], ex);
        }
    }
}

__global__ __launch_bounds__(128) void graph_ctx_kernel(
    const float* __restrict__ h, const int* __restrict__ goffs,
    const float* __restrict__ es, const float* __restrict__ gsum,
    float* __restrict__ ctx)
{
    int g = blockIdx.x, c = threadIdx.x;
    float invs = 1.f / (gsum[g] + 1e-16f);
    int b = goffs[g], e2 = goffs[g + 1];
    float acc = 0.f;
    for (int i = b; i < e2; ++i) acc = fmaf(es[i] * invs, h[(size_t)i * 128 + c], acc);
    ctx[(size_t)g * 128 + c] = acc;
}

extern "C" void kernel_launch(void* const* d_in, const int* in_sizes, int n_in,
                              void* d_out, int out_size, void* d_ws, size_t ws_size,
                              hipStream_t stream) {
    const float* x      = (const float*)d_in[0];
    const int*   ei     = (const int*)d_in[1];
    const float* ea     = (const float*)d_in[2];
    const int*   batch  = (const int*)d_in[3];
    const float* embW   = (const float*)d_in[4];
    const float* embB   = (const float*)d_in[5];
    const float* attW1  = (const float*)d_in[6];
    const float* attb1  = (const float*)d_in[7];
    const float* attW2  = (const float*)d_in[8];
    const float* attb2  = (const float*)d_in[9];
    const float* mlpW   = (const float*)d_in[10];
    const float* mlpb   = (const float*)d_in[11];
    const float* gWih   = (const float*)d_in[12];
    const float* gWhh   = (const float*)d_in[13];
    const float* gbih   = (const float*)d_in[14];
    const float* gbhh   = (const float*)d_in[15];
    const float* gattW1 = (const float*)d_in[16];
    const float* gattb1 = (const float*)d_in[17];
    const float* gattW2 = (const float*)d_in[18];
    const float* gattb2 = (const float*)d_in[19];
    const float* ggWih  = (const float*)d_in[20];
    const float* ggWhh  = (const float*)d_in[21];
    const float* ggbih  = (const float*)d_in[22];
    const float* ggbhh  = (const float*)d_in[23];
    float* out = (float*)d_out;

    void* basep = nullptr;
    (void)hipGetSymbolAddress(&basep, HIP_SYMBOL(g_afp_ws));
    char* base = (char*)basep;
    float* h0    = (float*)(base + OFF_H0);
    float* h1    = (float*)(base + OFF_H1);
    bf16*  h0b   = (bf16*)(base + OFF_H0B);
    bf16*  h1b   = (bf16*)(base + OFF_H1B);
    bf16*  xb    = (bf16*)(base + OFF_XB);
    bf16*  pqmb  = (bf16*)(base + OFF_PQMB);
    float* gh    = (float*)(base + OFF_GH);
    float* gi    = (float*)(base + OFF_GI);
    bf16*  aggrb = (bf16*)(base + OFF_AGB);
    float* es    = (float*)(base + OFF_ES);
    bf16*  wt    = (bf16*)(base + OFF_WT);
    bf16*  wiht  = (bf16*)(base + OFF_WIHT);
    bf16*  embt  = (bf16*)(base + OFF_EMBT);
    float* bbig  = (float*)(base + OFF_BBIG);
    float* g0b   = (float*)(base + OFF_G0);
    float* gAb   = (float*)(base + OFF_GA);
    float* ctx   = (float*)(base + OFF_CTX);
    float* gictx = (float*)(base + OFF_GICTX);
    float* ghb   = (float*)(base + OFF_GHB);
    float* gsum  = (float*)(base + OFF_GSUM);
    int*   deg   = (int*)(base + OFF_DEG);
    int*   offs  = (int*)(base + OFF_OFFS);
    int*   cur   = (int*)(base + OFF_CUR);
    int2*  cse   = (int2*)(base + OFF_CSE);
    int*   ghist = (int*)(base + OFF_GHIST);
    int*   goffs = (int*)(base + OFF_GOFFS);

    (void)hipMemsetAsync(deg, 0, SZ_NF, stream);
    (void)hipMemsetAsync(cur, 0, SZ_NF, stream);
    (void)hipMemsetAsync(ghist, 0, SZ_GF, stream);
    (void)hipMemsetAsync(gsum, 0, SZ_GF, stream);

    hist_dst_kernel<<<(N_EDGES + 255) / 256, 256, 0, stream>>>(ei, deg);
    scan_excl_kernel<<<1, 1024, 0, stream>>>(deg, offs, N_NODES);
    scatter_cse_kernel<<<(N_EDGES + 255) / 256, 256, 0, stream>>>(ei, offs, cur, cse);
    hist_batch_kernel<<<(N_NODES + 255) / 256, 256, 0, stream>>>(batch, ghist);
    scan_excl_kernel<<<1, 1024, 0, stream>>>(ghist, goffs, N_GRAPHS);

    cast_bf16_kernel<<<(N_NODES * FN + 255) / 256, 256, 0, stream>>>(x, xb, N_NODES * FN);
    transpose_cast<<<(FN * 128 + 255) / 256, 256, 0, stream>>>(embW, embt, FN, 128);

    {
        dim3 g((N_NODES + 63) / 64, 128 / 64);
        gemm_mfma<<<g, 256, 0, stream>>>(xb, embt, embB, h0, h0b, N_NODES, FN, 128, 1 | 4);
    }

    float* hcur = h0;  bf16* hcurb = h0b;
    float* hnext = h1; bf16* hnextb = h1b;
    for (int l = 0; l < NL; ++l) {
        pack_weights_bt<<<(768 * 128 + 255) / 256, 256, 0, stream>>>(
            attW1 + (size_t)l * 272 * 128, mlpW + (size_t)l * 144 * 128,
            gWhh + (size_t)l * 128 * 384, attb1 + l * 128, mlpb + l * 128,
            gbhh + l * 384, wt, bbig);
        {
            dim3 g((N_NODES + 63) / 64, 768 / 64);
            gemm_mfma<<<g, 256, 0, stream>>>(hcurb, wt, bbig, gh, pqmb,
                                             N_NODES, 128, 768, 2);
        }
        edge_fused_kernel<<<(N_NODES + 4 * DPW - 1) / (4 * DPW), 256, 0, stream>>>(
            pqmb, cse, ea, attW1 + (size_t)l * 272 * 128 + 256 * 128,
            attW2 + (size_t)l * 128, attb2 + l,
            mlpW + (size_t)l * 144 * 128 + 128 * 128,
            offs, aggrb);
        transpose_cast<<<(128 * 384 + 255) / 256, 256, 0, stream>>>(
            gWih + (size_t)l * 128 * 384, wiht, 128, 384);
        {
            dim3 g((N_NODES + 63) / 64, 384 / 64);
            gemm_mfma<<<g, 256, 0, stream>>>(aggrb, wiht, gbih + l * 384, gi, nullptr,
                                             N_NODES, 128, 384, 0);
        }
        gru_elem_kernel<<<((size_t)N_NODES * H + 255) / 256, 256, 0, stream>>>(
            gi, gh, hcur, hnext, hnextb, N_NODES);
        float* t = hcur; hcur = hnext; hnext = t;
        bf16* tb = hcurb; hcurb = hnextb; hnextb = tb;
    }

    graph_pool_sum<<<N_GRAPHS, 128, 0, stream>>>(hcur, goffs, g0b);
    node_score_kernel<<<(N_NODES + 7) / 8, 128, 0, stream>>>(
        hcur, gattW1, gattb1, gattW2, gattb2, batch, es, gsum);
    graph_ctx_kernel<<<N_GRAPHS, 128, 0, stream>>>(hcur, goffs, es, gsum, ctx);

    dim3 gg((N_GRAPHS + 63) / 64, 384 / 64);
    gemm_f32<<<gg, 256, 0, stream>>>(ctx, ggWih, ggbih, gictx, N_GRAPHS, H, 384);
    gemm_f32<<<gg, 256, 0, stream>>>(g0b, ggWhh, ggbhh, ghb, N_GRAPHS, H, 384);
    gru_elem_kernel<<<((size_t)N_GRAPHS * H + 255) / 256, 256, 0, stream>>>(
        gictx, ghb, g0b, gAb, nullptr, N_GRAPHS);
    gemm_f32<<<gg, 256, 0, stream>>>(gAb, ggWhh, ggbhh, ghb, N_GRAPHS, H, 384);
    gru_elem_kernel<<<((size_t)N_GRAPHS * H + 255) / 256, 256, 0, stream>>>(
        gictx, ghb, gAb, out, nullptr, N_GRAPHS);
}